// Round 2
// baseline (6260.320 us; speedup 1.0000x reference)
//
#include <hip/hip_runtime.h>

namespace {

constexpr int NN = 50000;   // nodes
constexpr int NE = 800000;  // edges
constexpr int NB = 64;      // graphs / batch
constexpr int NL = 32;      // path length
constexpr int ND = 256;     // D == H == 256

__device__ __forceinline__ float sigf(float x){ return 1.0f/(1.0f + __expf(-x)); }

// ---------------- degree ----------------
__global__ void k_deg(const int* __restrict__ dst, float* __restrict__ deg){
  int stride = gridDim.x * blockDim.x;
  for (int e = blockIdx.x*blockDim.x + threadIdx.x; e < NE; e += stride)
    unsafeAtomicAdd(&deg[dst[e]], 1.0f);
}

__global__ void k_rdeg(float* __restrict__ deg){
  int i = blockIdx.x*blockDim.x + threadIdx.x;
  if (i < NN) deg[i] = 1.0f / fmaxf(deg[i], 1.0f);
}

// ---------------- scatter-add of 256-dim features over edges ----------------
__global__ void k_scatter(const float* __restrict__ feat, const int* __restrict__ src,
                          const int* __restrict__ dst, float* __restrict__ agg){
  const long long total = (long long)NE * 64;   // edge x float4
  long long stride = (long long)gridDim.x * blockDim.x;
  for (long long i = (long long)blockIdx.x*blockDim.x + threadIdx.x; i < total; i += stride){
    int e  = (int)(i >> 6);
    int c4 = ((int)i & 63) * 4;
    int s = src[e], d = dst[e];         // wave-uniform (64 lanes share e) -> broadcast
    float4 v = *(const float4*)(feat + (long long)s*ND + c4);
    float* p = agg + (long long)d*ND + c4;
    unsafeAtomicAdd(p+0, v.x);
    unsafeAtomicAdd(p+1, v.y);
    unsafeAtomicAdd(p+2, v.z);
    unsafeAtomicAdd(p+3, v.w);
  }
}

// ---------------- fused SAGE GEMM: C = act((A1*rs)@W1 + bias + A2@W2) ----------------
// 64x256 block tile (BN=256 = full width, one block per row tile; block reads only its
// own rows and writes after the K-loop -> in-place C==A1 safe), 8x8 micro-tile, K=512.
__launch_bounds__(256, 3)
__global__ void k_gemm(const float* __restrict__ A1, const float* __restrict__ rs,
                       const float* __restrict__ W1, const float* __restrict__ A2,
                       const float* __restrict__ W2, const float* __restrict__ bias,
                       float* __restrict__ C, int relu)
{
  __shared__ float As[16][68];    // [k][m] transposed, padded (16B-aligned rows)
  __shared__ float Ws[16][256];   // [k][n]
  const int t  = threadIdx.x;
  const int m0 = blockIdx.x * 64;
  const int rg = t >> 5;          // 0..7  (row group; only 2 values per wave -> A broadcast)
  const int cg = t & 31;          // 0..31 (col group)
  const int sm = t >> 2;          // A-stage row 0..63
  const int sj = (t & 3) * 4;     // A-stage k offset
  const int wk = t >> 4;          // W-stage k row 0..15
  const int wn = (t & 15) * 16;   // W-stage col base

  float acc[8][8];
  #pragma unroll
  for (int i = 0; i < 8; ++i)
    #pragma unroll
    for (int j = 0; j < 8; ++j) acc[i][j] = 0.f;

  const int gm_s = m0 + sm;
  const bool mok = (gm_s < NN);
  const float r1 = mok ? rs[gm_s] : 0.f;
  const float* a1row = A1 + (long long)gm_s*ND;
  const float* a2row = A2 + (long long)gm_s*ND;

  for (int k0 = 0; k0 < 512; k0 += 16){
    const bool first = (k0 < 256);
    const int  kk    = first ? k0 : (k0 - 256);
    float4 av = make_float4(0.f,0.f,0.f,0.f);
    if (mok){
      av = first ? *(const float4*)(a1row + kk + sj)
                 : *(const float4*)(a2row + kk + sj);
      if (first){ av.x*=r1; av.y*=r1; av.z*=r1; av.w*=r1; }
    }
    const float* wp = (first ? W1 : W2) + (long long)(kk + wk)*ND + wn;
    float4 w0 = *(const float4*)(wp+0);
    float4 w1 = *(const float4*)(wp+4);
    float4 w2 = *(const float4*)(wp+8);
    float4 w3 = *(const float4*)(wp+12);
    __syncthreads();
    As[sj+0][sm] = av.x; As[sj+1][sm] = av.y; As[sj+2][sm] = av.z; As[sj+3][sm] = av.w;
    *(float4*)&Ws[wk][wn+ 0] = w0;
    *(float4*)&Ws[wk][wn+ 4] = w1;
    *(float4*)&Ws[wk][wn+ 8] = w2;
    *(float4*)&Ws[wk][wn+12] = w3;
    __syncthreads();
    #pragma unroll
    for (int k = 0; k < 16; ++k){
      float a[8], b[8];
      *(float4*)&a[0] = *(const float4*)&As[k][rg*8];
      *(float4*)&a[4] = *(const float4*)&As[k][rg*8+4];
      *(float4*)&b[0] = *(const float4*)&Ws[k][cg*8];
      *(float4*)&b[4] = *(const float4*)&Ws[k][cg*8+4];
      #pragma unroll
      for (int i = 0; i < 8; ++i)
        #pragma unroll
        for (int j = 0; j < 8; ++j)
          acc[i][j] = fmaf(a[i], b[j], acc[i][j]);
    }
  }

  float bv[8];
  #pragma unroll
  for (int j = 0; j < 8; ++j) bv[j] = bias[cg*8 + j];
  #pragma unroll
  for (int i = 0; i < 8; ++i){
    int gm = m0 + rg*8 + i;
    if (gm < NN){
      float o[8];
      #pragma unroll
      for (int j = 0; j < 8; ++j){
        float v = acc[i][j] + bv[j];
        o[j] = relu ? fmaxf(v, 0.f) : v;
      }
      *(float4*)(C + (long long)gm*ND + cg*8 + 0) = *(float4*)&o[0];
      *(float4*)(C + (long long)gm*ND + cg*8 + 4) = *(float4*)&o[4];
    }
  }
}

// ---------------- LSTM input gates: Xg[i][g] = emb[paths[i]] . w_ih[g] + b_ih[g]+b_hh[g] ----------------
__launch_bounds__(256, 3)
__global__ void k_xgate(const float* __restrict__ emb, const int* __restrict__ paths,
                        const float* __restrict__ w_ih, const float* __restrict__ b_ih,
                        const float* __restrict__ b_hh, float* __restrict__ xg)
{
  __shared__ float As[16][68];
  __shared__ float Ws[16][260];   // [k][g], transposed from w_ih rows
  const int t  = threadIdx.x;
  const int m0 = blockIdx.x * 64;    // path rows (2048 total)
  const int g0 = blockIdx.y * 256;   // gate cols (1024 total)
  const int rg = t >> 5, cg = t & 31;
  const int sm = t >> 2, sj = (t & 3) * 4;

  float acc[8][8];
  #pragma unroll
  for (int i = 0; i < 8; ++i)
    #pragma unroll
    for (int j = 0; j < 8; ++j) acc[i][j] = 0.f;

  const int node = paths[m0 + sm];
  const float* arow = emb  + (long long)node*ND;
  const float* wrow = w_ih + (long long)(g0 + t)*ND;

  for (int k0 = 0; k0 < 256; k0 += 16){
    float4 av = *(const float4*)(arow + k0 + sj);
    float4 q0 = *(const float4*)(wrow + k0 + 0);
    float4 q1 = *(const float4*)(wrow + k0 + 4);
    float4 q2 = *(const float4*)(wrow + k0 + 8);
    float4 q3 = *(const float4*)(wrow + k0 + 12);
    __syncthreads();
    As[sj+0][sm]=av.x; As[sj+1][sm]=av.y; As[sj+2][sm]=av.z; As[sj+3][sm]=av.w;
    Ws[ 0][t]=q0.x; Ws[ 1][t]=q0.y; Ws[ 2][t]=q0.z; Ws[ 3][t]=q0.w;
    Ws[ 4][t]=q1.x; Ws[ 5][t]=q1.y; Ws[ 6][t]=q1.z; Ws[ 7][t]=q1.w;
    Ws[ 8][t]=q2.x; Ws[ 9][t]=q2.y; Ws[10][t]=q2.z; Ws[11][t]=q2.w;
    Ws[12][t]=q3.x; Ws[13][t]=q3.y; Ws[14][t]=q3.z; Ws[15][t]=q3.w;
    __syncthreads();
    #pragma unroll
    for (int k = 0; k < 16; ++k){
      float a[8], b[8];
      *(float4*)&a[0] = *(const float4*)&As[k][rg*8];
      *(float4*)&a[4] = *(const float4*)&As[k][rg*8+4];
      *(float4*)&b[0] = *(const float4*)&Ws[k][cg*8];
      *(float4*)&b[4] = *(const float4*)&Ws[k][cg*8+4];
      #pragma unroll
      for (int i = 0; i < 8; ++i)
        #pragma unroll
        for (int j = 0; j < 8; ++j)
          acc[i][j] = fmaf(a[i], b[j], acc[i][j]);
    }
  }

  float bv[8];
  #pragma unroll
  for (int j = 0; j < 8; ++j){ int g = g0 + cg*8 + j; bv[j] = b_ih[g] + b_hh[g]; }
  #pragma unroll
  for (int i = 0; i < 8; ++i){
    int row = m0 + rg*8 + i;
    float o[8];
    #pragma unroll
    for (int j = 0; j < 8; ++j) o[j] = acc[i][j] + bv[j];
    *(float4*)(xg + (long long)row*1024 + g0 + cg*8 + 0) = *(float4*)&o[0];
    *(float4*)(xg + (long long)row*1024 + g0 + cg*8 + 4) = *(float4*)&o[4];
  }
}

// ---------------- one LSTM step ----------------
// block = (unit u, batch-half): grid 512 = 256 units x 2 halves of 32 batch rows.
// hs holds 32 x 256 h values at padded stride 260 (16B-aligned; read pattern 4b mod 32
// -> worst 4-way bank conflict). Fixes round-1 bug (stride 68 < row length 256).
__launch_bounds__(256, 4)
__global__ void k_lstm_step(const float* __restrict__ h_in, float* __restrict__ h_out,
                            float* __restrict__ c_state, const float* __restrict__ xg,
                            const float* __restrict__ w_hh, int tstep)
{
  __shared__ float ws[4*256];      // w_hh rows (i,f,g,o) for unit u
  __shared__ float hs[32*260];     // h rows b0..b0+31, padded stride 260
  __shared__ float part[2*128];    // [kd][b*4+g]
  __shared__ float gs[128];        // summed gate pre-activations [b*4+g]
  const int t  = threadIdx.x;
  const int u  = blockIdx.x >> 1;
  const int b0 = (blockIdx.x & 1) * 32;

  { // stage the 4 w_hh rows of unit u (i,f,g,o)
    int gate = t >> 6, c4 = (t & 63) * 4;
    float4 v = *(const float4*)(w_hh + (long long)(gate*256 + u)*256 + c4);
    *(float4*)&ws[gate*256 + c4] = v;
  }
  #pragma unroll
  for (int i = 0; i < 8; ++i){ // stage h (32 rows x 256 floats)
    int idx = i*256 + t;       // float4 index 0..2047
    int b = idx >> 6, c4 = (idx & 63) * 4;
    float4 v = *(const float4*)(h_in + (long long)(b0 + b)*256 + c4);
    *(float4*)&hs[b*260 + c4] = v;
  }
  __syncthreads();

  // thread -> (b, gate, k-half); partial dot over 128 k
  const int b  = t & 31;
  const int g  = (t >> 5) & 3;
  const int kd = t >> 7;           // 0..1
  float s = 0.f;
  const float* hp = &hs[b*260 + kd*128];
  const float* wp = &ws[g*256 + kd*128];
  #pragma unroll
  for (int k4 = 0; k4 < 32; ++k4){
    float4 h4 = *(const float4*)(hp + k4*4);
    float4 w4 = *(const float4*)(wp + k4*4);
    s += h4.x*w4.x + h4.y*w4.y + h4.z*w4.z + h4.w*w4.w;
  }
  part[kd*128 + b*4 + g] = s;
  __syncthreads();

  if (t < 128){
    int bb = t >> 2, gg = t & 3;
    const float* xp = xg + ((long long)(b0 + bb)*NL + tstep)*1024;
    gs[t] = part[t] + part[128 + t] + xp[gg*256 + u];
  }
  __syncthreads();

  if (t < 32){
    float gi = gs[t*4+0], gf = gs[t*4+1], gG = gs[t*4+2], go = gs[t*4+3];
    int bb = b0 + t;
    float c_old = c_state[bb*256 + u];
    float c_new = sigf(gf)*c_old + sigf(gi)*tanhf(gG);
    c_state[bb*256 + u] = c_new;
    h_out[bb*256 + u] = sigf(go)*tanhf(c_new);
  }
}

// ---------------- global mean pool (batch ids sorted -> run-length + rare atomics) ----------------
__global__ void k_pool(const float* __restrict__ emb, const int* __restrict__ batch,
                       float* __restrict__ gsum, float* __restrict__ gcnt)
{
  __shared__ int bs[256];
  const int t  = threadIdx.x;
  const int n0 = blockIdx.x * 256;
  {
    int n = n0 + t;
    bs[t] = (n < NN) ? batch[n] : -1;
  }
  __syncthreads();
  int cur = bs[0];
  float acc = 0.f; int cnt = 0;
  for (int j = 0; j < 256; ++j){
    int nn = n0 + j;
    if (nn >= NN) break;
    int g = bs[j];                 // uniform across block
    if (g != cur){
      unsafeAtomicAdd(&gsum[cur*256 + t], acc);
      if (t == 0) unsafeAtomicAdd(&gcnt[cur], (float)cnt);
      acc = 0.f; cnt = 0; cur = g;
    }
    acc += emb[(long long)nn*256 + t];
    ++cnt;
  }
  if (cnt > 0 && cur >= 0){
    unsafeAtomicAdd(&gsum[cur*256 + t], acc);
    if (t == 0) unsafeAtomicAdd(&gcnt[cur], (float)cnt);
  }
}

// ---------------- finalize pooling + concat [graph_emb, path_emb] ----------------
__global__ void k_final(const float* __restrict__ gsum, const float* __restrict__ gcnt,
                        const float* __restrict__ hfin, float* __restrict__ comb)
{
  const int b = blockIdx.x, t = threadIdx.x;
  float r = 1.0f / fmaxf(gcnt[b], 1.0f);
  comb[b*512 + t]       = gsum[b*256 + t] * r;
  comb[b*512 + 256 + t] = hfin[b*256 + t];
}

// ---------------- scorer MLP ----------------
__global__ void k_score(const float* __restrict__ comb, const float* __restrict__ wm1,
                        const float* __restrict__ bm1, const float* __restrict__ wm2,
                        const float* __restrict__ bm2, float* __restrict__ out)
{
  __shared__ float cs[512];
  __shared__ float red[4];
  const int b = blockIdx.x, t = threadIdx.x;
  if (t < 128) *(float4*)&cs[t*4] = *(const float4*)&comb[b*512 + t*4];
  __syncthreads();
  float v = 0.f;
  #pragma unroll 4
  for (int k = 0; k < 512; ++k) v = fmaf(cs[k], wm1[(long long)k*256 + t], v);
  v = fmaxf(v + bm1[t], 0.f) * wm2[t];
  #pragma unroll
  for (int off = 32; off > 0; off >>= 1) v += __shfl_down(v, off, 64);
  if ((t & 63) == 0) red[t >> 6] = v;
  __syncthreads();
  if (t == 0) out[b] = red[0] + red[1] + red[2] + red[3] + bm2[0];
}

} // namespace

extern "C" void kernel_launch(void* const* d_in, const int* in_sizes, int n_in,
                              void* d_out, int out_size, void* d_ws, size_t ws_size,
                              hipStream_t stream)
{
  const float* x     = (const float*)d_in[0];
  const int*   eidx  = (const int*)  d_in[1];
  const int*   batch = (const int*)  d_in[2];
  const int*   paths = (const int*)  d_in[3];
  const float* w1l   = (const float*)d_in[4];
  const float* b1l   = (const float*)d_in[5];
  const float* w1r   = (const float*)d_in[6];
  const float* w2l   = (const float*)d_in[7];
  const float* b2l   = (const float*)d_in[8];
  const float* w2r   = (const float*)d_in[9];
  const float* w_ih  = (const float*)d_in[10];
  const float* w_hh  = (const float*)d_in[11];
  const float* b_ih  = (const float*)d_in[12];
  const float* b_hh  = (const float*)d_in[13];
  const float* wm1   = (const float*)d_in[14];
  const float* bm1   = (const float*)d_in[15];
  const float* wm2   = (const float*)d_in[16];
  const float* bm2   = (const float*)d_in[17];

  const int* src = eidx;        // edge_index[0]
  const int* dst = eidx + NE;   // edge_index[1]

  // workspace layout (floats), all offsets 16B-aligned
  float* w    = (float*)d_ws;
  float* deg  = w;                         // 50048
  float* bufA = deg  + 50048;              // N*256 (agg/mean, then node_emb in-place)
  float* bufB = bufA + (long long)NN*ND;   // N*256 (h1)
  float* xg   = bufB + (long long)NN*ND;   // 2048*1024
  float* gsum = xg   + 2048*1024;          // 64*256
  float* gcnt = gsum + NB*ND;              // 64
  float* h0   = gcnt + 64;                 // 64*256
  float* c0   = h0   + NB*ND;              // 64*256
  float* h1   = c0   + NB*ND;              // 64*256
  float* comb = h1   + NB*ND;              // 64*512

  const size_t featBytes = (size_t)NN * ND * sizeof(float);

  // ---- layer 1 ----
  hipMemsetAsync(deg, 0, 50048*sizeof(float), stream);
  hipMemsetAsync(bufA, 0, featBytes, stream);
  k_deg<<<1024, 256, 0, stream>>>(dst, deg);
  k_rdeg<<<(NN+255)/256, 256, 0, stream>>>(deg);
  k_scatter<<<8192, 256, 0, stream>>>(x, src, dst, bufA);
  k_gemm<<<(NN+63)/64, 256, 0, stream>>>(bufA, deg, w1l, x, w1r, b1l, bufB, 1);

  // ---- layer 2 (node_emb written in-place over bufA) ----
  hipMemsetAsync(bufA, 0, featBytes, stream);
  k_scatter<<<8192, 256, 0, stream>>>(bufB, src, dst, bufA);
  k_gemm<<<(NN+63)/64, 256, 0, stream>>>(bufA, deg, w2l, bufB, w2r, b2l, bufA, 0);

  // ---- global mean pool ----
  hipMemsetAsync(gsum, 0, (NB*ND + 64)*sizeof(float), stream);
  k_pool<<<(NN+255)/256, 256, 0, stream>>>(bufA, batch, gsum, gcnt);

  // ---- LSTM input gates (paths gather + GEMM vs w_ih^T, biases folded) ----
  k_xgate<<<dim3((NB*NL)/64, 1024/256), 256, 0, stream>>>(bufA, paths, w_ih, b_ih, b_hh, xg);

  // ---- LSTM recurrence: 32 steps, ping-pong h buffers ----
  hipMemsetAsync(h0, 0, 2*(size_t)NB*ND*sizeof(float), stream);  // h0 + c0
  for (int ts = 0; ts < NL; ++ts){
    float* hin  = (ts & 1) ? h1 : h0;
    float* hout = (ts & 1) ? h0 : h1;
    k_lstm_step<<<512, 256, 0, stream>>>(hin, hout, c0, xg, w_hh, ts);
  }
  // ts=31 wrote h0 -> final hidden state

  // ---- concat + scorer ----
  k_final<<<NB, 256, 0, stream>>>(gsum, gcnt, h0, comb);
  k_score<<<NB, 256, 0, stream>>>(comb, wm1, bm1, wm2, bm2, (float*)d_out);
}

// Round 3
// 1129.227 us; speedup vs baseline: 5.5439x; 5.5439x over previous
//
#include <hip/hip_runtime.h>

namespace {

constexpr int NN = 50000;   // nodes
constexpr int NE = 800000;  // edges
constexpr int NB = 64;      // graphs / batch
constexpr int NL = 32;      // path length
constexpr int ND = 256;     // D == H == 256
constexpr int NSCAN = 196;  // ceil(50176/256) scan blocks (196*256 = 50176)

__device__ __forceinline__ float sigf(float x){ return 1.0f/(1.0f + __expf(-x)); }

// ================= CSR build (counting sort of edges by dst) =================
__global__ void k_hist(const int* __restrict__ dst, int* __restrict__ cnt){
  int stride = gridDim.x * blockDim.x;
  for (int e = blockIdx.x*blockDim.x + threadIdx.x; e < NE; e += stride)
    atomicAdd(&cnt[dst[e]], 1);
}

// per-256-block exclusive scan; block totals to bsum
__global__ void k_scan_block(const int* __restrict__ cnt, int* __restrict__ offs,
                             int* __restrict__ bsum){
  __shared__ int s[256];
  const int t = threadIdx.x, i = blockIdx.x*256 + t;
  int v = cnt[i];
  s[t] = v; __syncthreads();
  #pragma unroll
  for (int off = 1; off < 256; off <<= 1){
    int x = (t >= off) ? s[t-off] : 0;
    __syncthreads();
    s[t] += x;
    __syncthreads();
  }
  offs[i] = s[t] - v;                 // exclusive within block
  if (t == 255) bsum[blockIdx.x] = s[255];
}

__global__ void k_scan_top(const int* __restrict__ bsum, int* __restrict__ bsum2){
  __shared__ int s[256];
  const int t = threadIdx.x;
  int v = (t < NSCAN) ? bsum[t] : 0;
  s[t] = v; __syncthreads();
  #pragma unroll
  for (int off = 1; off < 256; off <<= 1){
    int x = (t >= off) ? s[t-off] : 0;
    __syncthreads();
    s[t] += x;
    __syncthreads();
  }
  if (t < NSCAN) bsum2[t] = s[t] - v; // exclusive
}

__global__ void k_scan_add(int* __restrict__ offs, const int* __restrict__ bsum2,
                           int* __restrict__ cursor){
  const int i = blockIdx.x*256 + threadIdx.x;
  int v = offs[i] + bsum2[blockIdx.x];
  offs[i] = v;
  cursor[i] = v;
}

__global__ void k_fill(const int* __restrict__ src, const int* __restrict__ dst,
                       int* __restrict__ cursor, int* __restrict__ csr){
  int stride = gridDim.x * blockDim.x;
  for (int e = blockIdx.x*blockDim.x + threadIdx.x; e < NE; e += stride){
    int d = dst[e];
    int pos = atomicAdd(&cursor[d], 1);
    csr[pos] = src[e];
  }
}

// ================= mean-aggregate gather: one block per dst node =================
__launch_bounds__(256, 8)
__global__ void k_gather(const float* __restrict__ feat, const int* __restrict__ offs,
                         const int* __restrict__ csr, float* __restrict__ out){
  const int u = blockIdx.x, t = threadIdx.x;
  const int beg = offs[u], end = offs[u+1];
  __shared__ int sidx[256];
  float acc = 0.f;
  for (int c = beg; c < end; c += 256){
    int n = min(256, end - c);
    __syncthreads();
    if (t < n) sidx[t] = csr[c + t];
    __syncthreads();
    int j = 0;
    for (; j + 4 <= n; j += 4){
      int s0 = sidx[j], s1 = sidx[j+1], s2 = sidx[j+2], s3 = sidx[j+3];
      float v0 = feat[(long long)s0*ND + t];
      float v1 = feat[(long long)s1*ND + t];
      float v2 = feat[(long long)s2*ND + t];
      float v3 = feat[(long long)s3*ND + t];
      acc += (v0 + v1) + (v2 + v3);
    }
    for (; j < n; ++j) acc += feat[(long long)sidx[j]*ND + t];
  }
  float d = (float)(end - beg);
  out[(long long)u*ND + t] = acc / fmaxf(d, 1.f);
}

// ---------------- fused SAGE GEMM: C = act(A1@W1 + bias + A2@W2) ----------------
// A1 = mean-aggregated features (already divided by degree). 64x256 block tile
// (BN=256 = full width; block reads only its own rows, writes after the K-loop ->
// in-place C==A1 safe), 8x8 micro-tile, K=512.
__launch_bounds__(256, 3)
__global__ void k_gemm(const float* __restrict__ A1, const float* __restrict__ W1,
                       const float* __restrict__ A2, const float* __restrict__ W2,
                       const float* __restrict__ bias, float* __restrict__ C, int relu)
{
  __shared__ float As[16][68];    // [k][m] transposed, padded (16B-aligned rows)
  __shared__ float Ws[16][256];   // [k][n]
  const int t  = threadIdx.x;
  const int m0 = blockIdx.x * 64;
  const int rg = t >> 5;          // 0..7  (row group; only 2 values per wave -> A broadcast)
  const int cg = t & 31;          // 0..31 (col group)
  const int sm = t >> 2;          // A-stage row 0..63
  const int sj = (t & 3) * 4;     // A-stage k offset
  const int wk = t >> 4;          // W-stage k row 0..15
  const int wn = (t & 15) * 16;   // W-stage col base

  float acc[8][8];
  #pragma unroll
  for (int i = 0; i < 8; ++i)
    #pragma unroll
    for (int j = 0; j < 8; ++j) acc[i][j] = 0.f;

  const int gm_s = m0 + sm;
  const bool mok = (gm_s < NN);
  const float* a1row = A1 + (long long)gm_s*ND;
  const float* a2row = A2 + (long long)gm_s*ND;

  for (int k0 = 0; k0 < 512; k0 += 16){
    const bool first = (k0 < 256);
    const int  kk    = first ? k0 : (k0 - 256);
    float4 av = make_float4(0.f,0.f,0.f,0.f);
    if (mok){
      av = first ? *(const float4*)(a1row + kk + sj)
                 : *(const float4*)(a2row + kk + sj);
    }
    const float* wp = (first ? W1 : W2) + (long long)(kk + wk)*ND + wn;
    float4 w0 = *(const float4*)(wp+0);
    float4 w1 = *(const float4*)(wp+4);
    float4 w2 = *(const float4*)(wp+8);
    float4 w3 = *(const float4*)(wp+12);
    __syncthreads();
    As[sj+0][sm] = av.x; As[sj+1][sm] = av.y; As[sj+2][sm] = av.z; As[sj+3][sm] = av.w;
    *(float4*)&Ws[wk][wn+ 0] = w0;
    *(float4*)&Ws[wk][wn+ 4] = w1;
    *(float4*)&Ws[wk][wn+ 8] = w2;
    *(float4*)&Ws[wk][wn+12] = w3;
    __syncthreads();
    #pragma unroll
    for (int k = 0; k < 16; ++k){
      float a[8], b[8];
      *(float4*)&a[0] = *(const float4*)&As[k][rg*8];
      *(float4*)&a[4] = *(const float4*)&As[k][rg*8+4];
      *(float4*)&b[0] = *(const float4*)&Ws[k][cg*8];
      *(float4*)&b[4] = *(const float4*)&Ws[k][cg*8+4];
      #pragma unroll
      for (int i = 0; i < 8; ++i)
        #pragma unroll
        for (int j = 0; j < 8; ++j)
          acc[i][j] = fmaf(a[i], b[j], acc[i][j]);
    }
  }

  float bv[8];
  #pragma unroll
  for (int j = 0; j < 8; ++j) bv[j] = bias[cg*8 + j];
  #pragma unroll
  for (int i = 0; i < 8; ++i){
    int gm = m0 + rg*8 + i;
    if (gm < NN){
      float o[8];
      #pragma unroll
      for (int j = 0; j < 8; ++j){
        float v = acc[i][j] + bv[j];
        o[j] = relu ? fmaxf(v, 0.f) : v;
      }
      *(float4*)(C + (long long)gm*ND + cg*8 + 0) = *(float4*)&o[0];
      *(float4*)(C + (long long)gm*ND + cg*8 + 4) = *(float4*)&o[4];
    }
  }
}

// ---------------- LSTM input gates: Xg[i][g] = emb[paths[i]] . w_ih[g] + b_ih[g]+b_hh[g] ----------------
__launch_bounds__(256, 3)
__global__ void k_xgate(const float* __restrict__ emb, const int* __restrict__ paths,
                        const float* __restrict__ w_ih, const float* __restrict__ b_ih,
                        const float* __restrict__ b_hh, float* __restrict__ xg)
{
  __shared__ float As[16][68];
  __shared__ float Ws[16][260];   // [k][g], transposed from w_ih rows
  const int t  = threadIdx.x;
  const int m0 = blockIdx.x * 64;    // path rows (2048 total)
  const int g0 = blockIdx.y * 256;   // gate cols (1024 total)
  const int rg = t >> 5, cg = t & 31;
  const int sm = t >> 2, sj = (t & 3) * 4;

  float acc[8][8];
  #pragma unroll
  for (int i = 0; i < 8; ++i)
    #pragma unroll
    for (int j = 0; j < 8; ++j) acc[i][j] = 0.f;

  const int node = paths[m0 + sm];
  const float* arow = emb  + (long long)node*ND;
  const float* wrow = w_ih + (long long)(g0 + t)*ND;

  for (int k0 = 0; k0 < 256; k0 += 16){
    float4 av = *(const float4*)(arow + k0 + sj);
    float4 q0 = *(const float4*)(wrow + k0 + 0);
    float4 q1 = *(const float4*)(wrow + k0 + 4);
    float4 q2 = *(const float4*)(wrow + k0 + 8);
    float4 q3 = *(const float4*)(wrow + k0 + 12);
    __syncthreads();
    As[sj+0][sm]=av.x; As[sj+1][sm]=av.y; As[sj+2][sm]=av.z; As[sj+3][sm]=av.w;
    Ws[ 0][t]=q0.x; Ws[ 1][t]=q0.y; Ws[ 2][t]=q0.z; Ws[ 3][t]=q0.w;
    Ws[ 4][t]=q1.x; Ws[ 5][t]=q1.y; Ws[ 6][t]=q1.z; Ws[ 7][t]=q1.w;
    Ws[ 8][t]=q2.x; Ws[ 9][t]=q2.y; Ws[10][t]=q2.z; Ws[11][t]=q2.w;
    Ws[12][t]=q3.x; Ws[13][t]=q3.y; Ws[14][t]=q3.z; Ws[15][t]=q3.w;
    __syncthreads();
    #pragma unroll
    for (int k = 0; k < 16; ++k){
      float a[8], b[8];
      *(float4*)&a[0] = *(const float4*)&As[k][rg*8];
      *(float4*)&a[4] = *(const float4*)&As[k][rg*8+4];
      *(float4*)&b[0] = *(const float4*)&Ws[k][cg*8];
      *(float4*)&b[4] = *(const float4*)&Ws[k][cg*8+4];
      #pragma unroll
      for (int i = 0; i < 8; ++i)
        #pragma unroll
        for (int j = 0; j < 8; ++j)
          acc[i][j] = fmaf(a[i], b[j], acc[i][j]);
    }
  }

  float bv[8];
  #pragma unroll
  for (int j = 0; j < 8; ++j){ int g = g0 + cg*8 + j; bv[j] = b_ih[g] + b_hh[g]; }
  #pragma unroll
  for (int i = 0; i < 8; ++i){
    int row = m0 + rg*8 + i;
    float o[8];
    #pragma unroll
    for (int j = 0; j < 8; ++j) o[j] = acc[i][j] + bv[j];
    *(float4*)(xg + (long long)row*1024 + g0 + cg*8 + 0) = *(float4*)&o[0];
    *(float4*)(xg + (long long)row*1024 + g0 + cg*8 + 4) = *(float4*)&o[4];
  }
}

// ---------------- one LSTM step ----------------
// block = (unit u, batch-half): grid 512 = 256 units x 2 halves of 32 batch rows.
__launch_bounds__(256, 4)
__global__ void k_lstm_step(const float* __restrict__ h_in, float* __restrict__ h_out,
                            float* __restrict__ c_state, const float* __restrict__ xg,
                            const float* __restrict__ w_hh, int tstep)
{
  __shared__ float ws[4*256];      // w_hh rows (i,f,g,o) for unit u
  __shared__ float hs[32*260];     // h rows b0..b0+31, padded stride 260
  __shared__ float part[2*128];    // [kd][b*4+g]
  __shared__ float gs[128];        // summed gate pre-activations [b*4+g]
  const int t  = threadIdx.x;
  const int u  = blockIdx.x >> 1;
  const int b0 = (blockIdx.x & 1) * 32;

  { // stage the 4 w_hh rows of unit u (i,f,g,o)
    int gate = t >> 6, c4 = (t & 63) * 4;
    float4 v = *(const float4*)(w_hh + (long long)(gate*256 + u)*256 + c4);
    *(float4*)&ws[gate*256 + c4] = v;
  }
  #pragma unroll
  for (int i = 0; i < 8; ++i){ // stage h (32 rows x 256 floats)
    int idx = i*256 + t;       // float4 index 0..2047
    int b = idx >> 6, c4 = (idx & 63) * 4;
    float4 v = *(const float4*)(h_in + (long long)(b0 + b)*256 + c4);
    *(float4*)&hs[b*260 + c4] = v;
  }
  __syncthreads();

  const int b  = t & 31;
  const int g  = (t >> 5) & 3;
  const int kd = t >> 7;           // 0..1
  float s = 0.f;
  const float* hp = &hs[b*260 + kd*128];
  const float* wp = &ws[g*256 + kd*128];
  #pragma unroll
  for (int k4 = 0; k4 < 32; ++k4){
    float4 h4 = *(const float4*)(hp + k4*4);
    float4 w4 = *(const float4*)(wp + k4*4);
    s += h4.x*w4.x + h4.y*w4.y + h4.z*w4.z + h4.w*w4.w;
  }
  part[kd*128 + b*4 + g] = s;
  __syncthreads();

  if (t < 128){
    int bb = t >> 2, gg = t & 3;
    const float* xp = xg + ((long long)(b0 + bb)*NL + tstep)*1024;
    gs[t] = part[t] + part[128 + t] + xp[gg*256 + u];
  }
  __syncthreads();

  if (t < 32){
    float gi = gs[t*4+0], gf = gs[t*4+1], gG = gs[t*4+2], go = gs[t*4+3];
    int bb = b0 + t;
    float c_old = c_state[bb*256 + u];
    float c_new = sigf(gf)*c_old + sigf(gi)*tanhf(gG);
    c_state[bb*256 + u] = c_new;
    h_out[bb*256 + u] = sigf(go)*tanhf(c_new);
  }
}

// ---------------- global mean pool (batch ids sorted -> run-length + rare atomics) ----------------
__global__ void k_pool(const float* __restrict__ emb, const int* __restrict__ batch,
                       float* __restrict__ gsum, float* __restrict__ gcnt)
{
  __shared__ int bs[256];
  const int t  = threadIdx.x;
  const int n0 = blockIdx.x * 256;
  {
    int n = n0 + t;
    bs[t] = (n < NN) ? batch[n] : -1;
  }
  __syncthreads();
  int cur = bs[0];
  float acc = 0.f; int cnt = 0;
  for (int j = 0; j < 256; ++j){
    int nn = n0 + j;
    if (nn >= NN) break;
    int g = bs[j];                 // uniform across block
    if (g != cur){
      unsafeAtomicAdd(&gsum[cur*256 + t], acc);
      if (t == 0) unsafeAtomicAdd(&gcnt[cur], (float)cnt);
      acc = 0.f; cnt = 0; cur = g;
    }
    acc += emb[(long long)nn*256 + t];
    ++cnt;
  }
  if (cnt > 0 && cur >= 0){
    unsafeAtomicAdd(&gsum[cur*256 + t], acc);
    if (t == 0) unsafeAtomicAdd(&gcnt[cur], (float)cnt);
  }
}

// ---------------- finalize pooling + concat [graph_emb, path_emb] ----------------
__global__ void k_final(const float* __restrict__ gsum, const float* __restrict__ gcnt,
                        const float* __restrict__ hfin, float* __restrict__ comb)
{
  const int b = blockIdx.x, t = threadIdx.x;
  float r = 1.0f / fmaxf(gcnt[b], 1.0f);
  comb[b*512 + t]       = gsum[b*256 + t] * r;
  comb[b*512 + 256 + t] = hfin[b*256 + t];
}

// ---------------- scorer MLP ----------------
__global__ void k_score(const float* __restrict__ comb, const float* __restrict__ wm1,
                        const float* __restrict__ bm1, const float* __restrict__ wm2,
                        const float* __restrict__ bm2, float* __restrict__ out)
{
  __shared__ float cs[512];
  __shared__ float red[4];
  const int b = blockIdx.x, t = threadIdx.x;
  if (t < 128) *(float4*)&cs[t*4] = *(const float4*)&comb[b*512 + t*4];
  __syncthreads();
  float v = 0.f;
  #pragma unroll 4
  for (int k = 0; k < 512; ++k) v = fmaf(cs[k], wm1[(long long)k*256 + t], v);
  v = fmaxf(v + bm1[t], 0.f) * wm2[t];
  #pragma unroll
  for (int off = 32; off > 0; off >>= 1) v += __shfl_down(v, off, 64);
  if ((t & 63) == 0) red[t >> 6] = v;
  __syncthreads();
  if (t == 0) out[b] = red[0] + red[1] + red[2] + red[3] + bm2[0];
}

} // namespace

extern "C" void kernel_launch(void* const* d_in, const int* in_sizes, int n_in,
                              void* d_out, int out_size, void* d_ws, size_t ws_size,
                              hipStream_t stream)
{
  const float* x     = (const float*)d_in[0];
  const int*   eidx  = (const int*)  d_in[1];
  const int*   batch = (const int*)  d_in[2];
  const int*   paths = (const int*)  d_in[3];
  const float* w1l   = (const float*)d_in[4];
  const float* b1l   = (const float*)d_in[5];
  const float* w1r   = (const float*)d_in[6];
  const float* w2l   = (const float*)d_in[7];
  const float* b2l   = (const float*)d_in[8];
  const float* w2r   = (const float*)d_in[9];
  const float* w_ih  = (const float*)d_in[10];
  const float* w_hh  = (const float*)d_in[11];
  const float* b_ih  = (const float*)d_in[12];
  const float* b_hh  = (const float*)d_in[13];
  const float* wm1   = (const float*)d_in[14];
  const float* bm1   = (const float*)d_in[15];
  const float* wm2   = (const float*)d_in[16];
  const float* bm2   = (const float*)d_in[17];

  const int* src = eidx;        // edge_index[0]
  const int* dst = eidx + NE;   // edge_index[1]

  // workspace layout (floats), all offsets 16B-aligned
  float* w    = (float*)d_ws;
  float* bufA = w;                         // N*256 (mean agg, then node_emb in-place)
  float* bufB = bufA + (long long)NN*ND;   // N*256 (h1)
  float* xg   = bufB + (long long)NN*ND;   // 2048*1024 floats
  float* gsum = xg   + 2048*1024;          // 64*256
  float* gcnt = gsum + NB*ND;              // 64
  float* h0   = gcnt + 64;                 // 64*256
  float* c0   = h0   + NB*ND;              // 64*256
  float* h1   = c0   + NB*ND;              // 64*256
  float* comb = h1   + NB*ND;              // 64*512

  // CSR scratch aliased into xg region (dead until k_xgate runs, after layer 2):
  // 3*50432 + 512 + 800000 = 951,808 ints < 2,097,152 floats available.
  int* cnt    = (int*)xg;        // 50432 (zero-padded to 50176 used)
  int* offs   = cnt    + 50432;  // 50432
  int* cursor = offs   + 50432;  // 50432
  int* bsum   = cursor + 50432;  // 256
  int* bsum2  = bsum   + 256;    // 256
  int* csr    = bsum2  + 256;    // 800000

  // ---- build CSR (counting sort by dst), shared by both layers ----
  hipMemsetAsync(cnt, 0, 50432*sizeof(int), stream);
  k_hist<<<1024, 256, 0, stream>>>(dst, cnt);
  k_scan_block<<<NSCAN, 256, 0, stream>>>(cnt, offs, bsum);
  k_scan_top<<<1, 256, 0, stream>>>(bsum, bsum2);
  k_scan_add<<<NSCAN, 256, 0, stream>>>(offs, bsum2, cursor);
  k_fill<<<1024, 256, 0, stream>>>(src, dst, cursor, csr);

  // ---- layer 1: gather-mean then fused GEMM ----
  k_gather<<<NN, 256, 0, stream>>>(x, offs, csr, bufA);
  k_gemm<<<(NN+63)/64, 256, 0, stream>>>(bufA, w1l, x, w1r, b1l, bufB, 1);

  // ---- layer 2 (node_emb written in-place over bufA) ----
  k_gather<<<NN, 256, 0, stream>>>(bufB, offs, csr, bufA);
  k_gemm<<<(NN+63)/64, 256, 0, stream>>>(bufA, w2l, bufB, w2r, b2l, bufA, 0);

  // ---- global mean pool ----
  hipMemsetAsync(gsum, 0, (NB*ND + 64)*sizeof(float), stream);
  k_pool<<<(NN+255)/256, 256, 0, stream>>>(bufA, batch, gsum, gcnt);

  // ---- LSTM input gates (paths gather + GEMM vs w_ih^T, biases folded) ----
  // overwrites the CSR alias region — CSR is dead by now
  k_xgate<<<dim3((NB*NL)/64, 1024/256), 256, 0, stream>>>(bufA, paths, w_ih, b_ih, b_hh, xg);

  // ---- LSTM recurrence: 32 steps, ping-pong h buffers ----
  hipMemsetAsync(h0, 0, 2*(size_t)NB*ND*sizeof(float), stream);  // h0 + c0
  for (int ts = 0; ts < NL; ++ts){
    float* hin  = (ts & 1) ? h1 : h0;
    float* hout = (ts & 1) ? h0 : h1;
    k_lstm_step<<<512, 256, 0, stream>>>(hin, hout, c0, xg, w_hh, ts);
  }
  // ts=31 wrote h0 -> final hidden state

  // ---- concat + scorer ----
  k_final<<<NB, 256, 0, stream>>>(gsum, gcnt, h0, comb);
  k_score<<<NB, 256, 0, stream>>>(comb, wm1, bm1, wm2, bm2, (float*)d_out);
}

// Round 4
// 1122.482 us; speedup vs baseline: 5.5772x; 1.0060x over previous
//
#include <hip/hip_runtime.h>

namespace {

constexpr int NN = 50000;   // nodes
constexpr int NE = 800000;  // edges
constexpr int NB = 64;      // graphs / batch
constexpr int NL = 32;      // path length
constexpr int ND = 256;     // D == H == 256
constexpr int NSCAN = 196;  // ceil(50176/256) scan blocks

typedef __attribute__((ext_vector_type(8))) short short8v;  // 8 bf16 (4 VGPRs)
typedef __attribute__((ext_vector_type(4))) float float4v;  // MFMA accumulator

__device__ __forceinline__ float sigf(float x){ return 1.0f/(1.0f + __expf(-x)); }

// split 8 fp32 -> 8 bf16-hi (truncated; exact bits) + 8 bf16-lo (of remainder)
__device__ __forceinline__ void split8(float4 fa, float4 fb, uint4& h, uint4& lo){
  uint a0=__float_as_uint(fa.x), a1=__float_as_uint(fa.y), a2=__float_as_uint(fa.z), a3=__float_as_uint(fa.w);
  uint b0=__float_as_uint(fb.x), b1=__float_as_uint(fb.y), b2=__float_as_uint(fb.z), b3=__float_as_uint(fb.w);
  h.x = (a0>>16) | (a1 & 0xFFFF0000u);
  h.y = (a2>>16) | (a3 & 0xFFFF0000u);
  h.z = (b0>>16) | (b1 & 0xFFFF0000u);
  h.w = (b2>>16) | (b3 & 0xFFFF0000u);
  float r0 = fa.x - __uint_as_float(a0 & 0xFFFF0000u);
  float r1 = fa.y - __uint_as_float(a1 & 0xFFFF0000u);
  float r2 = fa.z - __uint_as_float(a2 & 0xFFFF0000u);
  float r3 = fa.w - __uint_as_float(a3 & 0xFFFF0000u);
  float r4 = fb.x - __uint_as_float(b0 & 0xFFFF0000u);
  float r5 = fb.y - __uint_as_float(b1 & 0xFFFF0000u);
  float r6 = fb.z - __uint_as_float(b2 & 0xFFFF0000u);
  float r7 = fb.w - __uint_as_float(b3 & 0xFFFF0000u);
  lo.x = (__float_as_uint(r0)>>16) | (__float_as_uint(r1) & 0xFFFF0000u);
  lo.y = (__float_as_uint(r2)>>16) | (__float_as_uint(r3) & 0xFFFF0000u);
  lo.z = (__float_as_uint(r4)>>16) | (__float_as_uint(r5) & 0xFFFF0000u);
  lo.w = (__float_as_uint(r6)>>16) | (__float_as_uint(r7) & 0xFFFF0000u);
}

// ================= CSR build (counting sort of edges by dst) =================
__global__ void k_hist(const int* __restrict__ dst, int* __restrict__ cnt){
  int stride = gridDim.x * blockDim.x;
  for (int e = blockIdx.x*blockDim.x + threadIdx.x; e < NE; e += stride)
    atomicAdd(&cnt[dst[e]], 1);
}

__global__ void k_scan_block(const int* __restrict__ cnt, int* __restrict__ offs,
                             int* __restrict__ bsum){
  __shared__ int s[256];
  const int t = threadIdx.x, i = blockIdx.x*256 + t;
  int v = cnt[i];
  s[t] = v; __syncthreads();
  #pragma unroll
  for (int off = 1; off < 256; off <<= 1){
    int x = (t >= off) ? s[t-off] : 0;
    __syncthreads();
    s[t] += x;
    __syncthreads();
  }
  offs[i] = s[t] - v;
  if (t == 255) bsum[blockIdx.x] = s[255];
}

__global__ void k_scan_top(const int* __restrict__ bsum, int* __restrict__ bsum2){
  __shared__ int s[256];
  const int t = threadIdx.x;
  int v = (t < NSCAN) ? bsum[t] : 0;
  s[t] = v; __syncthreads();
  #pragma unroll
  for (int off = 1; off < 256; off <<= 1){
    int x = (t >= off) ? s[t-off] : 0;
    __syncthreads();
    s[t] += x;
    __syncthreads();
  }
  if (t < NSCAN) bsum2[t] = s[t] - v;
}

__global__ void k_scan_add(int* __restrict__ offs, const int* __restrict__ bsum2,
                           int* __restrict__ cursor){
  const int i = blockIdx.x*256 + threadIdx.x;
  int v = offs[i] + bsum2[blockIdx.x];
  offs[i] = v;
  cursor[i] = v;
}

__global__ void k_fill(const int* __restrict__ src, const int* __restrict__ dst,
                       int* __restrict__ cursor, int* __restrict__ csr){
  int stride = gridDim.x * blockDim.x;
  for (int e = blockIdx.x*blockDim.x + threadIdx.x; e < NE; e += stride){
    int d = dst[e];
    int pos = atomicAdd(&cursor[d], 1);
    csr[pos] = src[e];
  }
}

// ================= mean-aggregate gather: one block per dst node =================
__launch_bounds__(256, 8)
__global__ void k_gather(const float* __restrict__ feat, const int* __restrict__ offs,
                         const int* __restrict__ csr, float* __restrict__ out){
  const int u = blockIdx.x, t = threadIdx.x;
  const int beg = offs[u], end = offs[u+1];
  __shared__ int sidx[256];
  float acc = 0.f;
  for (int c = beg; c < end; c += 256){
    int n = min(256, end - c);
    __syncthreads();
    if (t < n) sidx[t] = csr[c + t];
    __syncthreads();
    int j = 0;
    for (; j + 4 <= n; j += 4){
      int s0 = sidx[j], s1 = sidx[j+1], s2 = sidx[j+2], s3 = sidx[j+3];
      float v0 = feat[(long long)s0*ND + t];
      float v1 = feat[(long long)s1*ND + t];
      float v2 = feat[(long long)s2*ND + t];
      float v3 = feat[(long long)s3*ND + t];
      acc += (v0 + v1) + (v2 + v3);
    }
    for (; j < n; ++j) acc += feat[(long long)sidx[j]*ND + t];
  }
  float d = (float)(end - beg);
  out[(long long)u*ND + t] = acc / fmaxf(d, 1.f);
}

// ============ weight prep: Wt[n][k0..511] = [wl; wr][k][n], split hi/lo bf16 ============
__global__ void k_wsplit(const float* __restrict__ wl, const float* __restrict__ wr,
                         ushort* __restrict__ WtH, ushort* __restrict__ WtL){
  const int k = blockIdx.x;    // 0..511
  const int n = threadIdx.x;   // 0..255
  float v = (k < 256) ? wl[k*256 + n] : wr[(k-256)*256 + n];
  uint u = __float_as_uint(v);
  float r = v - __uint_as_float(u & 0xFFFF0000u);
  WtH[n*512 + k] = (ushort)(u >> 16);
  WtL[n*512 + k] = (ushort)(__float_as_uint(r) >> 16);
}

// ============ MFMA SAGE GEMM: C = act([A1|A2] @ Wt^T + bias) (bf16 3-term split) ============
// Block: 64 rows x 256 cols, 4 waves; wave w covers cols w*64..w*64+63 (4 n-tiles of 16).
// K = 512 (A1 cols 0..255, A2 cols 256..511), BK = 32 (one MFMA k-step).
// LDS in fragment order -> conflict-free ds_read_b128. In-place C==A1 safe (block-private rows,
// write after K-loop).
__launch_bounds__(256, 2)
__global__ void k_gemm_mfma(const float* __restrict__ A1, const float* __restrict__ A2,
                            const ushort* __restrict__ WtH, const ushort* __restrict__ WtL,
                            const float* __restrict__ bias, float* __restrict__ C, int relu)
{
  __shared__ ushort AsH[4*512];    // [mt][lane][8]  (4 KB)
  __shared__ ushort AsL[4*512];
  __shared__ ushort BsH[16*512];   // [nt][lane][8]  (16 KB)
  __shared__ ushort BsL[16*512];

  const int t = threadIdx.x;
  const int w = t >> 6;            // wave 0..3
  const int l = t & 63;            // lane
  const int m0 = blockIdx.x * 64;

  const float4v vzero = {0.f, 0.f, 0.f, 0.f};
  float4v acc[4][4];
  #pragma unroll
  for (int i = 0; i < 4; ++i)
    #pragma unroll
    for (int j = 0; j < 4; ++j) acc[i][j] = vzero;

  // A-stage assignment: thread -> (row am, k-group akg)
  const int am  = t >> 2;          // 0..63
  const int akg = t & 3;           // 0..3 (8 k each)
  const int gm  = m0 + am;
  const bool mok = gm < NN;
  const int aci = (am >> 4)*64 + (am & 15) + akg*16;   // A LDS chunk (16B units)

  for (int kk = 0; kk < 16; ++kk){
    const int kb = kk * 32;
    // ---- load A chunk (8 fp32) and split ----
    uint4 ah4 = {0,0,0,0}, al4 = {0,0,0,0};
    if (mok){
      const float* ap = (kb < 256 ? A1 + (long long)gm*ND + kb
                                  : A2 + (long long)gm*ND + (kb - 256)) + akg*8;
      float4 fa = *(const float4*)ap;
      float4 fb = *(const float4*)(ap + 4);
      split8(fa, fb, ah4, al4);
    }
    // ---- load B chunks (Wt is [n][512] bf16, k-contiguous) ----
    uint4 bh4[4], bl4[4];
    int bci[4];
    #pragma unroll
    for (int p = 0; p < 4; ++p){
      int c = p*256 + t;
      int n = c >> 2, kg = c & 3;
      bci[p] = (n >> 4)*64 + (n & 15) + kg*16;
      const int off = (n << 9) + kb + kg*8;
      bh4[p] = *(const uint4*)(WtH + off);
      bl4[p] = *(const uint4*)(WtL + off);
    }
    __syncthreads();   // previous iteration's LDS reads complete
    ((uint4*)AsH)[aci] = ah4;
    ((uint4*)AsL)[aci] = al4;
    #pragma unroll
    for (int p = 0; p < 4; ++p){
      ((uint4*)BsH)[bci[p]] = bh4[p];
      ((uint4*)BsL)[bci[p]] = bl4[p];
    }
    __syncthreads();
    // ---- fragments + MFMA ----
    short8v ah[4], al[4];
    #pragma unroll
    for (int mt = 0; mt < 4; ++mt){
      ah[mt] = *(short8v*)&AsH[(mt*64 + l)*8];
      al[mt] = *(short8v*)&AsL[(mt*64 + l)*8];
    }
    #pragma unroll
    for (int nt = 0; nt < 4; ++nt){
      short8v bh = *(short8v*)&BsH[((w*4 + nt)*64 + l)*8];
      short8v bl = *(short8v*)&BsL[((w*4 + nt)*64 + l)*8];
      #pragma unroll
      for (int mt = 0; mt < 4; ++mt){
        acc[mt][nt] = __builtin_amdgcn_mfma_f32_16x16x32_bf16(ah[mt], bh, acc[mt][nt], 0, 0, 0);
        acc[mt][nt] = __builtin_amdgcn_mfma_f32_16x16x32_bf16(al[mt], bh, acc[mt][nt], 0, 0, 0);
        acc[mt][nt] = __builtin_amdgcn_mfma_f32_16x16x32_bf16(ah[mt], bl, acc[mt][nt], 0, 0, 0);
      }
    }
  }

  // ---- epilogue: C/D layout col=lane&15, row=(lane>>4)*4+reg ----
  const int q  = l >> 4;
  const int cl = l & 15;
  #pragma unroll
  for (int nt = 0; nt < 4; ++nt){
    const int col = w*64 + nt*16 + cl;
    const float bv = bias[col];
    #pragma unroll
    for (int mt = 0; mt < 4; ++mt){
      const int row0 = m0 + mt*16 + q*4;
      #pragma unroll
      for (int r = 0; r < 4; ++r){
        int row = row0 + r;
        if (row < NN){
          float v = acc[mt][nt][r] + bv;
          if (relu) v = fmaxf(v, 0.f);
          C[(long long)row*ND + col] = v;
        }
      }
    }
  }
}

// ---------------- LSTM input gates: Xg[i][g] = emb[paths[i]] . w_ih[g] + b_ih[g]+b_hh[g] ----------------
__launch_bounds__(256, 3)
__global__ void k_xgate(const float* __restrict__ emb, const int* __restrict__ paths,
                        const float* __restrict__ w_ih, const float* __restrict__ b_ih,
                        const float* __restrict__ b_hh, float* __restrict__ xg)
{
  __shared__ float As[16][68];
  __shared__ float Ws[16][260];
  const int t  = threadIdx.x;
  const int m0 = blockIdx.x * 64;    // path rows (2048 total)
  const int g0 = blockIdx.y * 256;   // gate cols (1024 total)
  const int rg = t >> 5, cg = t & 31;
  const int sm = t >> 2, sj = (t & 3) * 4;

  float acc[8][8];
  #pragma unroll
  for (int i = 0; i < 8; ++i)
    #pragma unroll
    for (int j = 0; j < 8; ++j) acc[i][j] = 0.f;

  const int node = paths[m0 + sm];
  const float* arow = emb  + (long long)node*ND;
  const float* wrow = w_ih + (long long)(g0 + t)*ND;

  for (int k0 = 0; k0 < 256; k0 += 16){
    float4 av = *(const float4*)(arow + k0 + sj);
    float4 q0 = *(const float4*)(wrow + k0 + 0);
    float4 q1 = *(const float4*)(wrow + k0 + 4);
    float4 q2 = *(const float4*)(wrow + k0 + 8);
    float4 q3 = *(const float4*)(wrow + k0 + 12);
    __syncthreads();
    As[sj+0][sm]=av.x; As[sj+1][sm]=av.y; As[sj+2][sm]=av.z; As[sj+3][sm]=av.w;
    Ws[ 0][t]=q0.x; Ws[ 1][t]=q0.y; Ws[ 2][t]=q0.z; Ws[ 3][t]=q0.w;
    Ws[ 4][t]=q1.x; Ws[ 5][t]=q1.y; Ws[ 6][t]=q1.z; Ws[ 7][t]=q1.w;
    Ws[ 8][t]=q2.x; Ws[ 9][t]=q2.y; Ws[10][t]=q2.z; Ws[11][t]=q2.w;
    Ws[12][t]=q3.x; Ws[13][t]=q3.y; Ws[14][t]=q3.z; Ws[15][t]=q3.w;
    __syncthreads();
    #pragma unroll
    for (int k = 0; k < 16; ++k){
      float a[8], b[8];
      *(float4*)&a[0] = *(const float4*)&As[k][rg*8];
      *(float4*)&a[4] = *(const float4*)&As[k][rg*8+4];
      *(float4*)&b[0] = *(const float4*)&Ws[k][cg*8];
      *(float4*)&b[4] = *(const float4*)&Ws[k][cg*8+4];
      #pragma unroll
      for (int i = 0; i < 8; ++i)
        #pragma unroll
        for (int j = 0; j < 8; ++j)
          acc[i][j] = fmaf(a[i], b[j], acc[i][j]);
    }
  }

  float bv[8];
  #pragma unroll
  for (int j = 0; j < 8; ++j){ int g = g0 + cg*8 + j; bv[j] = b_ih[g] + b_hh[g]; }
  #pragma unroll
  for (int i = 0; i < 8; ++i){
    int row = m0 + rg*8 + i;
    float o[8];
    #pragma unroll
    for (int j = 0; j < 8; ++j) o[j] = acc[i][j] + bv[j];
    *(float4*)(xg + (long long)row*1024 + g0 + cg*8 + 0) = *(float4*)&o[0];
    *(float4*)(xg + (long long)row*1024 + g0 + cg*8 + 4) = *(float4*)&o[4];
  }
}

// ---------------- one LSTM step ----------------
__launch_bounds__(256, 4)
__global__ void k_lstm_step(const float* __restrict__ h_in, float* __restrict__ h_out,
                            float* __restrict__ c_state, const float* __restrict__ xg,
                            const float* __restrict__ w_hh, int tstep)
{
  __shared__ float ws[4*256];
  __shared__ float hs[32*260];
  __shared__ float part[2*128];
  __shared__ float gs[128];
  const int t  = threadIdx.x;
  const int u  = blockIdx.x >> 1;
  const int b0 = (blockIdx.x & 1) * 32;

  {
    int gate = t >> 6, c4 = (t & 63) * 4;
    float4 v = *(const float4*)(w_hh + (long long)(gate*256 + u)*256 + c4);
    *(float4*)&ws[gate*256 + c4] = v;
  }
  #pragma unroll
  for (int i = 0; i < 8; ++i){
    int idx = i*256 + t;
    int b = idx >> 6, c4 = (idx & 63) * 4;
    float4 v = *(const float4*)(h_in + (long long)(b0 + b)*256 + c4);
    *(float4*)&hs[b*260 + c4] = v;
  }
  __syncthreads();

  const int b  = t & 31;
  const int g  = (t >> 5) & 3;
  const int kd = t >> 7;
  float s = 0.f;
  const float* hp = &hs[b*260 + kd*128];
  const float* wp = &ws[g*256 + kd*128];
  #pragma unroll
  for (int k4 = 0; k4 < 32; ++k4){
    float4 h4 = *(const float4*)(hp + k4*4);
    float4 w4 = *(const float4*)(wp + k4*4);
    s += h4.x*w4.x + h4.y*w4.y + h4.z*w4.z + h4.w*w4.w;
  }
  part[kd*128 + b*4 + g] = s;
  __syncthreads();

  if (t < 128){
    int bb = t >> 2, gg = t & 3;
    const float* xp = xg + ((long long)(b0 + bb)*NL + tstep)*1024;
    gs[t] = part[t] + part[128 + t] + xp[gg*256 + u];
  }
  __syncthreads();

  if (t < 32){
    float gi = gs[t*4+0], gf = gs[t*4+1], gG = gs[t*4+2], go = gs[t*4+3];
    int bb = b0 + t;
    float c_old = c_state[bb*256 + u];
    float c_new = sigf(gf)*c_old + sigf(gi)*tanhf(gG);
    c_state[bb*256 + u] = c_new;
    h_out[bb*256 + u] = sigf(go)*tanhf(c_new);
  }
}

// ---------------- global mean pool ----------------
__global__ void k_pool(const float* __restrict__ emb, const int* __restrict__ batch,
                       float* __restrict__ gsum, float* __restrict__ gcnt)
{
  __shared__ int bs[256];
  const int t  = threadIdx.x;
  const int n0 = blockIdx.x * 256;
  {
    int n = n0 + t;
    bs[t] = (n < NN) ? batch[n] : -1;
  }
  __syncthreads();
  int cur = bs[0];
  float acc = 0.f; int cnt = 0;
  for (int j = 0; j < 256; ++j){
    int nn = n0 + j;
    if (nn >= NN) break;
    int g = bs[j];
    if (g != cur){
      unsafeAtomicAdd(&gsum[cur*256 + t], acc);
      if (t == 0) unsafeAtomicAdd(&gcnt[cur], (float)cnt);
      acc = 0.f; cnt = 0; cur = g;
    }
    acc += emb[(long long)nn*256 + t];
    ++cnt;
  }
  if (cnt > 0 && cur >= 0){
    unsafeAtomicAdd(&gsum[cur*256 + t], acc);
    if (t == 0) unsafeAtomicAdd(&gcnt[cur], (float)cnt);
  }
}

// ---------------- finalize pooling + concat ----------------
__global__ void k_final(const float* __restrict__ gsum, const float* __restrict__ gcnt,
                        const float* __restrict__ hfin, float* __restrict__ comb)
{
  const int b = blockIdx.x, t = threadIdx.x;
  float r = 1.0f / fmaxf(gcnt[b], 1.0f);
  comb[b*512 + t]       = gsum[b*256 + t] * r;
  comb[b*512 + 256 + t] = hfin[b*256 + t];
}

// ---------------- scorer MLP ----------------
__global__ void k_score(const float* __restrict__ comb, const float* __restrict__ wm1,
                        const float* __restrict__ bm1, const float* __restrict__ wm2,
                        const float* __restrict__ bm2, float* __restrict__ out)
{
  __shared__ float cs[512];
  __shared__ float red[4];
  const int b = blockIdx.x, t = threadIdx.x;
  if (t < 128) *(float4*)&cs[t*4] = *(const float4*)&comb[b*512 + t*4];
  __syncthreads();
  float v = 0.f;
  #pragma unroll 4
  for (int k = 0; k < 512; ++k) v = fmaf(cs[k], wm1[(long long)k*256 + t], v);
  v = fmaxf(v + bm1[t], 0.f) * wm2[t];
  #pragma unroll
  for (int off = 32; off > 0; off >>= 1) v += __shfl_down(v, off, 64);
  if ((t & 63) == 0) red[t >> 6] = v;
  __syncthreads();
  if (t == 0) out[b] = red[0] + red[1] + red[2] + red[3] + bm2[0];
}

} // namespace

extern "C" void kernel_launch(void* const* d_in, const int* in_sizes, int n_in,
                              void* d_out, int out_size, void* d_ws, size_t ws_size,
                              hipStream_t stream)
{
  const float* x     = (const float*)d_in[0];
  const int*   eidx  = (const int*)  d_in[1];
  const int*   batch = (const int*)  d_in[2];
  const int*   paths = (const int*)  d_in[3];
  const float* w1l   = (const float*)d_in[4];
  const float* b1l   = (const float*)d_in[5];
  const float* w1r   = (const float*)d_in[6];
  const float* w2l   = (const float*)d_in[7];
  const float* b2l   = (const float*)d_in[8];
  const float* w2r   = (const float*)d_in[9];
  const float* w_ih  = (const float*)d_in[10];
  const float* w_hh  = (const float*)d_in[11];
  const float* b_ih  = (const float*)d_in[12];
  const float* b_hh  = (const float*)d_in[13];
  const float* wm1   = (const float*)d_in[14];
  const float* bm1   = (const float*)d_in[15];
  const float* wm2   = (const float*)d_in[16];
  const float* bm2   = (const float*)d_in[17];

  const int* src = eidx;        // edge_index[0]
  const int* dst = eidx + NE;   // edge_index[1]

  // workspace layout (floats), offsets multiples of 16 floats
  float* w    = (float*)d_ws;
  float* bufA = w;                         // N*256 (mean agg; layer-2 output in-place)
  float* bufB = bufA + (long long)NN*ND;   // N*256 (h1)
  float* xg   = bufB + (long long)NN*ND;   // 2048*1024 floats
  float* gsum = xg   + 2048*1024;          // 64*256
  float* gcnt = gsum + NB*ND;              // 64
  float* h0   = gcnt + 64;                 // 64*256
  float* c0   = h0   + NB*ND;              // 64*256
  float* h1   = c0   + NB*ND;              // 64*256
  float* comb = h1   + NB*ND;              // 64*512
  ushort* wt1H = (ushort*)(comb + NB*512); // 256*512 each (bf16)
  ushort* wt1L = wt1H + 256*512;
  ushort* wt2H = wt1L + 256*512;
  ushort* wt2L = wt2H + 256*512;

  // CSR scratch aliased into xg region (dead until k_xgate runs, after layer 2)
  int* cnt    = (int*)xg;        // 50432
  int* offs   = cnt    + 50432;  // 50432
  int* cursor = offs   + 50432;  // 50432
  int* bsum   = cursor + 50432;  // 256
  int* bsum2  = bsum   + 256;    // 256
  int* csr    = bsum2  + 256;    // 800000

  // ---- weight prep (transpose + bf16 hi/lo split) ----
  k_wsplit<<<512, 256, 0, stream>>>(w1l, w1r, wt1H, wt1L);
  k_wsplit<<<512, 256, 0, stream>>>(w2l, w2r, wt2H, wt2L);

  // ---- build CSR (counting sort by dst), shared by both layers ----
  hipMemsetAsync(cnt, 0, 50432*sizeof(int), stream);
  k_hist<<<1024, 256, 0, stream>>>(dst, cnt);
  k_scan_block<<<NSCAN, 256, 0, stream>>>(cnt, offs, bsum);
  k_scan_top<<<1, 256, 0, stream>>>(bsum, bsum2);
  k_scan_add<<<NSCAN, 256, 0, stream>>>(offs, bsum2, cursor);
  k_fill<<<1024, 256, 0, stream>>>(src, dst, cursor, csr);

  // ---- layer 1: gather-mean then MFMA GEMM ----
  k_gather<<<NN, 256, 0, stream>>>(x, offs, csr, bufA);
  k_gemm_mfma<<<(NN+63)/64, 256, 0, stream>>>(bufA, x, wt1H, wt1L, b1l, bufB, 1);

  // ---- layer 2 (node_emb written in-place over bufA) ----
  k_gather<<<NN, 256, 0, stream>>>(bufB, offs, csr, bufA);
  k_gemm_mfma<<<(NN+63)/64, 256, 0, stream>>>(bufA, bufB, wt2H, wt2L, b2l, bufA, 0);

  // ---- global mean pool ----
  hipMemsetAsync(gsum, 0, (NB*ND + 64)*sizeof(float), stream);
  k_pool<<<(NN+255)/256, 256, 0, stream>>>(bufA, batch, gsum, gcnt);

  // ---- LSTM input gates (overwrites the CSR alias region — CSR dead by now) ----
  k_xgate<<<dim3((NB*NL)/64, 1024/256), 256, 0, stream>>>(bufA, paths, w_ih, b_ih, b_hh, xg);

  // ---- LSTM recurrence: 32 steps, ping-pong h buffers ----
  hipMemsetAsync(h0, 0, 2*(size_t)NB*ND*sizeof(float), stream);  // h0 + c0
  for (int ts = 0; ts < NL; ++ts){
    float* hin  = (ts & 1) ? h1 : h0;
    float* hout = (ts & 1) ? h0 : h1;
    k_lstm_step<<<512, 256, 0, stream>>>(hin, hout, c0, xg, w_hh, ts);
  }

  // ---- concat + scorer ----
  k_final<<<NB, 256, 0, stream>>>(gsum, gcnt, h0, comb);
  k_score<<<NB, 256, 0, stream>>>(comb, wm1, bm1, wm2, bm2, (float*)d_out);
}

// Round 5
// 1031.749 us; speedup vs baseline: 6.0677x; 1.0879x over previous
//
#include <hip/hip_runtime.h>

namespace {

constexpr int NN = 50000;   // nodes
constexpr int NE = 800000;  // edges
constexpr int NB = 64;      // graphs / batch
constexpr int NL = 32;      // path length
constexpr int ND = 256;     // D == H == 256
constexpr int NSCAN = 196;  // ceil(50176/256) scan blocks

typedef __attribute__((ext_vector_type(8))) short short8v;  // 8 bf16 (4 VGPRs)
typedef __attribute__((ext_vector_type(4))) float float4v;  // MFMA accumulator

__device__ __forceinline__ float sigf(float x){ return 1.0f/(1.0f + __expf(-x)); }

// split 8 fp32 -> 8 bf16-hi (truncated; exact bits) + 8 bf16-lo (of remainder)
__device__ __forceinline__ void split8(float4 fa, float4 fb, uint4& h, uint4& lo){
  uint a0=__float_as_uint(fa.x), a1=__float_as_uint(fa.y), a2=__float_as_uint(fa.z), a3=__float_as_uint(fa.w);
  uint b0=__float_as_uint(fb.x), b1=__float_as_uint(fb.y), b2=__float_as_uint(fb.z), b3=__float_as_uint(fb.w);
  h.x = (a0>>16) | (a1 & 0xFFFF0000u);
  h.y = (a2>>16) | (a3 & 0xFFFF0000u);
  h.z = (b0>>16) | (b1 & 0xFFFF0000u);
  h.w = (b2>>16) | (b3 & 0xFFFF0000u);
  float r0 = fa.x - __uint_as_float(a0 & 0xFFFF0000u);
  float r1 = fa.y - __uint_as_float(a1 & 0xFFFF0000u);
  float r2 = fa.z - __uint_as_float(a2 & 0xFFFF0000u);
  float r3 = fa.w - __uint_as_float(a3 & 0xFFFF0000u);
  float r4 = fb.x - __uint_as_float(b0 & 0xFFFF0000u);
  float r5 = fb.y - __uint_as_float(b1 & 0xFFFF0000u);
  float r6 = fb.z - __uint_as_float(b2 & 0xFFFF0000u);
  float r7 = fb.w - __uint_as_float(b3 & 0xFFFF0000u);
  lo.x = (__float_as_uint(r0)>>16) | (__float_as_uint(r1) & 0xFFFF0000u);
  lo.y = (__float_as_uint(r2)>>16) | (__float_as_uint(r3) & 0xFFFF0000u);
  lo.z = (__float_as_uint(r4)>>16) | (__float_as_uint(r5) & 0xFFFF0000u);
  lo.w = (__float_as_uint(r6)>>16) | (__float_as_uint(r7) & 0xFFFF0000u);
}

// ================= CSR build (counting sort of edges by dst) =================
__global__ void k_hist(const int* __restrict__ dst, int* __restrict__ cnt){
  int stride = gridDim.x * blockDim.x;
  for (int e = blockIdx.x*blockDim.x + threadIdx.x; e < NE; e += stride)
    atomicAdd(&cnt[dst[e]], 1);
}

__global__ void k_scan_block(const int* __restrict__ cnt, int* __restrict__ offs,
                             int* __restrict__ bsum){
  __shared__ int s[256];
  const int t = threadIdx.x, i = blockIdx.x*256 + t;
  int v = cnt[i];
  s[t] = v; __syncthreads();
  #pragma unroll
  for (int off = 1; off < 256; off <<= 1){
    int x = (t >= off) ? s[t-off] : 0;
    __syncthreads();
    s[t] += x;
    __syncthreads();
  }
  offs[i] = s[t] - v;
  if (t == 255) bsum[blockIdx.x] = s[255];
}

__global__ void k_scan_top(const int* __restrict__ bsum, int* __restrict__ bsum2){
  __shared__ int s[256];
  const int t = threadIdx.x;
  int v = (t < NSCAN) ? bsum[t] : 0;
  s[t] = v; __syncthreads();
  #pragma unroll
  for (int off = 1; off < 256; off <<= 1){
    int x = (t >= off) ? s[t-off] : 0;
    __syncthreads();
    s[t] += x;
    __syncthreads();
  }
  if (t < NSCAN) bsum2[t] = s[t] - v;
}

__global__ void k_scan_add(int* __restrict__ offs, const int* __restrict__ bsum2,
                           int* __restrict__ cursor){
  const int i = blockIdx.x*256 + threadIdx.x;
  int v = offs[i] + bsum2[blockIdx.x];
  offs[i] = v;
  cursor[i] = v;
}

__global__ void k_fill(const int* __restrict__ src, const int* __restrict__ dst,
                       int* __restrict__ cursor, int* __restrict__ csr){
  int stride = gridDim.x * blockDim.x;
  for (int e = blockIdx.x*blockDim.x + threadIdx.x; e < NE; e += stride){
    int d = dst[e];
    int pos = atomicAdd(&cursor[d], 1);
    csr[pos] = src[e];
  }
}

// ================= mean-aggregate gather: one block per dst node =================
__launch_bounds__(256, 8)
__global__ void k_gather(const float* __restrict__ feat, const int* __restrict__ offs,
                         const int* __restrict__ csr, float* __restrict__ out){
  const int u = blockIdx.x, t = threadIdx.x;
  const int beg = offs[u], end = offs[u+1];
  __shared__ int sidx[256];
  float acc = 0.f;
  for (int c = beg; c < end; c += 256){
    int n = min(256, end - c);
    __syncthreads();
    if (t < n) sidx[t] = csr[c + t];
    __syncthreads();
    int j = 0;
    for (; j + 4 <= n; j += 4){
      int s0 = sidx[j], s1 = sidx[j+1], s2 = sidx[j+2], s3 = sidx[j+3];
      float v0 = feat[(long long)s0*ND + t];
      float v1 = feat[(long long)s1*ND + t];
      float v2 = feat[(long long)s2*ND + t];
      float v3 = feat[(long long)s3*ND + t];
      acc += (v0 + v1) + (v2 + v3);
    }
    for (; j < n; ++j) acc += feat[(long long)sidx[j]*ND + t];
  }
  float d = (float)(end - beg);
  out[(long long)u*ND + t] = acc / fmaxf(d, 1.f);
}

// ============ weight prep: Wt[n][k0..511] = [wl; wr][k][n], split hi/lo bf16 ============
__global__ void k_wsplit(const float* __restrict__ wl, const float* __restrict__ wr,
                         ushort* __restrict__ WtH, ushort* __restrict__ WtL){
  const int k = blockIdx.x;    // 0..511
  const int n = threadIdx.x;   // 0..255
  float v = (k < 256) ? wl[k*256 + n] : wr[(k-256)*256 + n];
  uint u = __float_as_uint(v);
  float r = v - __uint_as_float(u & 0xFFFF0000u);
  WtH[n*512 + k] = (ushort)(u >> 16);
  WtL[n*512 + k] = (ushort)(__float_as_uint(r) >> 16);
}

// ============ MFMA SAGE GEMM (barrier-free main loop, direct fragment loads) ============
// C = act([A1|A2] @ Wt^T + bias), bf16 3-term split. Block: 64 rows x 256 cols, 4 waves;
// wave w covers cols w*64..w*64+63 (4 n-tiles). K=512, BK=32.
// A-fragment: lane l loads A[m0+mt*16+(l&15)][kb+(l>>4)*8 ..+8] (2x float4, coalesced
// 16 rows x 128B) and splits in-register. B-fragment: lane l loads
// Wt[n0+(l&15)][kb+(l>>4)*8 ..+8] (16B, L2-resident, same for all blocks).
// A and B use the same k-index formula -> any quad permutation cancels in the dot.
// Epilogue stages 16x256 slabs through LDS (stride 260 -> 2-way worst, free) for
// fully-coalesced float4 C writes. In-place C==A1 safe (block-private rows,
// stores after K-loop). NN = 50000 is a multiple of 16 -> all tile guards wave-uniform.
__launch_bounds__(256, 2)
__global__ void k_gemm_mfma(const float* __restrict__ A1, const float* __restrict__ A2,
                            const ushort* __restrict__ WtH, const ushort* __restrict__ WtL,
                            const float* __restrict__ bias, float* __restrict__ C, int relu)
{
  __shared__ float eb[16*260];     // epilogue staging (16.6 KB)
  const int t  = threadIdx.x;
  const int w  = t >> 6;           // wave 0..3
  const int l  = t & 63;           // lane
  const int lm = l & 15;           // m (A) / n (B) within 16-tile
  const int lq = l >> 4;           // quad -> k-offset group (x8)
  const int m0 = blockIdx.x * 64;

  const float4v vzero = {0.f, 0.f, 0.f, 0.f};
  float4v acc[4][4];
  #pragma unroll
  for (int i = 0; i < 4; ++i)
    #pragma unroll
    for (int j = 0; j < 4; ++j) acc[i][j] = vzero;

  bool mok[4];
  long long arow[4];
  #pragma unroll
  for (int mt = 0; mt < 4; ++mt){
    int row = m0 + mt*16 + lm;
    mok[mt]  = (m0 + mt*16) < NN;      // uniform (NN % 16 == 0)
    arow[mt] = (long long)row * ND;
  }
  int boff[4];
  #pragma unroll
  for (int nt = 0; nt < 4; ++nt) boff[nt] = (w*64 + nt*16 + lm) << 9;  // *512

  for (int kk = 0; kk < 16; ++kk){
    const int kb = kk * 32;
    const float* Abase = (kb < 256) ? A1 : A2;
    const int koff = (kb & 255) + lq*8;
    const int kb2  = kb + lq*8;

    // ---- B fragments: direct 16B loads (issue early) ----
    uint4 bhv[4], blv[4];
    #pragma unroll
    for (int nt = 0; nt < 4; ++nt){
      bhv[nt] = *(const uint4*)(WtH + boff[nt] + kb2);
      blv[nt] = *(const uint4*)(WtL + boff[nt] + kb2);
    }
    // ---- A fragments: direct loads + in-register split ----
    uint4 ahv[4], alv[4];
    #pragma unroll
    for (int mt = 0; mt < 4; ++mt){
      uint4 h4 = {0,0,0,0}, l4 = {0,0,0,0};
      if (mok[mt]){
        const float* p = Abase + arow[mt] + koff;
        float4 fa = *(const float4*)p;
        float4 fb = *(const float4*)(p + 4);
        split8(fa, fb, h4, l4);
      }
      ahv[mt] = h4; alv[mt] = l4;
    }
    // ---- MFMAs ----
    #pragma unroll
    for (int nt = 0; nt < 4; ++nt){
      short8v bh = *(short8v*)&bhv[nt];
      short8v bl = *(short8v*)&blv[nt];
      #pragma unroll
      for (int mt = 0; mt < 4; ++mt){
        short8v ah = *(short8v*)&ahv[mt];
        short8v al = *(short8v*)&alv[mt];
        acc[mt][nt] = __builtin_amdgcn_mfma_f32_16x16x32_bf16(ah, bh, acc[mt][nt], 0, 0, 0);
        acc[mt][nt] = __builtin_amdgcn_mfma_f32_16x16x32_bf16(al, bh, acc[mt][nt], 0, 0, 0);
        acc[mt][nt] = __builtin_amdgcn_mfma_f32_16x16x32_bf16(ah, bl, acc[mt][nt], 0, 0, 0);
      }
    }
  }

  // ---- epilogue: LDS transpose per 16-row slab, coalesced float4 stores ----
  float bvv[4];
  #pragma unroll
  for (int nt = 0; nt < 4; ++nt) bvv[nt] = bias[w*64 + nt*16 + lm];

  #pragma unroll
  for (int mt = 0; mt < 4; ++mt){
    #pragma unroll
    for (int nt = 0; nt < 4; ++nt){
      #pragma unroll
      for (int r = 0; r < 4; ++r){
        float v = acc[mt][nt][r] + bvv[nt];
        if (relu) v = fmaxf(v, 0.f);
        eb[(lq*4 + r)*260 + w*64 + nt*16 + lm] = v;   // C/D: col=lane&15, row=quad*4+reg
      }
    }
    __syncthreads();
    #pragma unroll
    for (int i = 0; i < 4; ++i){
      int idx = i*256 + t;           // 0..1023
      int rr  = idx >> 6;            // 0..15
      int c4  = (idx & 63) * 4;      // 0..252
      int grow = m0 + mt*16 + rr;
      if (grow < NN)
        *(float4*)(C + (long long)grow*ND + c4) = *(float4*)&eb[rr*260 + c4];
    }
    __syncthreads();
  }
}

// ---------------- LSTM input gates: Xg[i][g] = emb[paths[i]] . w_ih[g] + b_ih[g]+b_hh[g] ----------------
__launch_bounds__(256, 3)
__global__ void k_xgate(const float* __restrict__ emb, const int* __restrict__ paths,
                        const float* __restrict__ w_ih, const float* __restrict__ b_ih,
                        const float* __restrict__ b_hh, float* __restrict__ xg)
{
  __shared__ float As[16][68];
  __shared__ float Ws[16][260];
  const int t  = threadIdx.x;
  const int m0 = blockIdx.x * 64;    // path rows (2048 total)
  const int g0 = blockIdx.y * 256;   // gate cols (1024 total)
  const int rg = t >> 5, cg = t & 31;
  const int sm = t >> 2, sj = (t & 3) * 4;

  float acc[8][8];
  #pragma unroll
  for (int i = 0; i < 8; ++i)
    #pragma unroll
    for (int j = 0; j < 8; ++j) acc[i][j] = 0.f;

  const int node = paths[m0 + sm];
  const float* arow = emb  + (long long)node*ND;
  const float* wrow = w_ih + (long long)(g0 + t)*ND;

  for (int k0 = 0; k0 < 256; k0 += 16){
    float4 av = *(const float4*)(arow + k0 + sj);
    float4 q0 = *(const float4*)(wrow + k0 + 0);
    float4 q1 = *(const float4*)(wrow + k0 + 4);
    float4 q2 = *(const float4*)(wrow + k0 + 8);
    float4 q3 = *(const float4*)(wrow + k0 + 12);
    __syncthreads();
    As[sj+0][sm]=av.x; As[sj+1][sm]=av.y; As[sj+2][sm]=av.z; As[sj+3][sm]=av.w;
    Ws[ 0][t]=q0.x; Ws[ 1][t]=q0.y; Ws[ 2][t]=q0.z; Ws[ 3][t]=q0.w;
    Ws[ 4][t]=q1.x; Ws[ 5][t]=q1.y; Ws[ 6][t]=q1.z; Ws[ 7][t]=q1.w;
    Ws[ 8][t]=q2.x; Ws[ 9][t]=q2.y; Ws[10][t]=q2.z; Ws[11][t]=q2.w;
    Ws[12][t]=q3.x; Ws[13][t]=q3.y; Ws[14][t]=q3.z; Ws[15][t]=q3.w;
    __syncthreads();
    #pragma unroll
    for (int k = 0; k < 16; ++k){
      float a[8], b[8];
      *(float4*)&a[0] = *(const float4*)&As[k][rg*8];
      *(float4*)&a[4] = *(const float4*)&As[k][rg*8+4];
      *(float4*)&b[0] = *(const float4*)&Ws[k][cg*8];
      *(float4*)&b[4] = *(const float4*)&Ws[k][cg*8+4];
      #pragma unroll
      for (int i = 0; i < 8; ++i)
        #pragma unroll
        for (int j = 0; j < 8; ++j)
          acc[i][j] = fmaf(a[i], b[j], acc[i][j]);
    }
  }

  float bv[8];
  #pragma unroll
  for (int j = 0; j < 8; ++j){ int g = g0 + cg*8 + j; bv[j] = b_ih[g] + b_hh[g]; }
  #pragma unroll
  for (int i = 0; i < 8; ++i){
    int row = m0 + rg*8 + i;
    float o[8];
    #pragma unroll
    for (int j = 0; j < 8; ++j) o[j] = acc[i][j] + bv[j];
    *(float4*)(xg + (long long)row*1024 + g0 + cg*8 + 0) = *(float4*)&o[0];
    *(float4*)(xg + (long long)row*1024 + g0 + cg*8 + 4) = *(float4*)&o[4];
  }
}

// ---------------- one LSTM step ----------------
__launch_bounds__(256, 4)
__global__ void k_lstm_step(const float* __restrict__ h_in, float* __restrict__ h_out,
                            float* __restrict__ c_state, const float* __restrict__ xg,
                            const float* __restrict__ w_hh, int tstep)
{
  __shared__ float ws[4*256];
  __shared__ float hs[32*260];
  __shared__ float part[2*128];
  __shared__ float gs[128];
  const int t  = threadIdx.x;
  const int u  = blockIdx.x >> 1;
  const int b0 = (blockIdx.x & 1) * 32;

  {
    int gate = t >> 6, c4 = (t & 63) * 4;
    float4 v = *(const float4*)(w_hh + (long long)(gate*256 + u)*256 + c4);
    *(float4*)&ws[gate*256 + c4] = v;
  }
  #pragma unroll
  for (int i = 0; i < 8; ++i){
    int idx = i*256 + t;
    int b = idx >> 6, c4 = (idx & 63) * 4;
    float4 v = *(const float4*)(h_in + (long long)(b0 + b)*256 + c4);
    *(float4*)&hs[b*260 + c4] = v;
  }
  __syncthreads();

  const int b  = t & 31;
  const int g  = (t >> 5) & 3;
  const int kd = t >> 7;
  float s = 0.f;
  const float* hp = &hs[b*260 + kd*128];
  const float* wp = &ws[g*256 + kd*128];
  #pragma unroll
  for (int k4 = 0; k4 < 32; ++k4){
    float4 h4 = *(const float4*)(hp + k4*4);
    float4 w4 = *(const float4*)(wp + k4*4);
    s += h4.x*w4.x + h4.y*w4.y + h4.z*w4.z + h4.w*w4.w;
  }
  part[kd*128 + b*4 + g] = s;
  __syncthreads();

  if (t < 128){
    int bb = t >> 2, gg = t & 3;
    const float* xp = xg + ((long long)(b0 + bb)*NL + tstep)*1024;
    gs[t] = part[t] + part[128 + t] + xp[gg*256 + u];
  }
  __syncthreads();

  if (t < 32){
    float gi = gs[t*4+0], gf = gs[t*4+1], gG = gs[t*4+2], go = gs[t*4+3];
    int bb = b0 + t;
    float c_old = c_state[bb*256 + u];
    float c_new = sigf(gf)*c_old + sigf(gi)*tanhf(gG);
    c_state[bb*256 + u] = c_new;
    h_out[bb*256 + u] = sigf(go)*tanhf(c_new);
  }
}

// ---------------- global mean pool ----------------
__global__ void k_pool(const float* __restrict__ emb, const int* __restrict__ batch,
                       float* __restrict__ gsum, float* __restrict__ gcnt)
{
  __shared__ int bs[256];
  const int t  = threadIdx.x;
  const int n0 = blockIdx.x * 256;
  {
    int n = n0 + t;
    bs[t] = (n < NN) ? batch[n] : -1;
  }
  __syncthreads();
  int cur = bs[0];
  float acc = 0.f; int cnt = 0;
  for (int j = 0; j < 256; ++j){
    int nn = n0 + j;
    if (nn >= NN) break;
    int g = bs[j];
    if (g != cur){
      unsafeAtomicAdd(&gsum[cur*256 + t], acc);
      if (t == 0) unsafeAtomicAdd(&gcnt[cur], (float)cnt);
      acc = 0.f; cnt = 0; cur = g;
    }
    acc += emb[(long long)nn*256 + t];
    ++cnt;
  }
  if (cnt > 0 && cur >= 0){
    unsafeAtomicAdd(&gsum[cur*256 + t], acc);
    if (t == 0) unsafeAtomicAdd(&gcnt[cur], (float)cnt);
  }
}

// ---------------- finalize pooling + concat ----------------
__global__ void k_final(const float* __restrict__ gsum, const float* __restrict__ gcnt,
                        const float* __restrict__ hfin, float* __restrict__ comb)
{
  const int b = blockIdx.x, t = threadIdx.x;
  float r = 1.0f / fmaxf(gcnt[b], 1.0f);
  comb[b*512 + t]       = gsum[b*256 + t] * r;
  comb[b*512 + 256 + t] = hfin[b*256 + t];
}

// ---------------- scorer MLP ----------------
__global__ void k_score(const float* __restrict__ comb, const float* __restrict__ wm1,
                        const float* __restrict__ bm1, const float* __restrict__ wm2,
                        const float* __restrict__ bm2, float* __restrict__ out)
{
  __shared__ float cs[512];
  __shared__ float red[4];
  const int b = blockIdx.x, t = threadIdx.x;
  if (t < 128) *(float4*)&cs[t*4] = *(const float4*)&comb[b*512 + t*4];
  __syncthreads();
  float v = 0.f;
  #pragma unroll 4
  for (int k = 0; k < 512; ++k) v = fmaf(cs[k], wm1[(long long)k*256 + t], v);
  v = fmaxf(v + bm1[t], 0.f) * wm2[t];
  #pragma unroll
  for (int off = 32; off > 0; off >>= 1) v += __shfl_down(v, off, 64);
  if ((t & 63) == 0) red[t >> 6] = v;
  __syncthreads();
  if (t == 0) out[b] = red[0] + red[1] + red[2] + red[3] + bm2[0];
}

} // namespace

extern "C" void kernel_launch(void* const* d_in, const int* in_sizes, int n_in,
                              void* d_out, int out_size, void* d_ws, size_t ws_size,
                              hipStream_t stream)
{
  const float* x     = (const float*)d_in[0];
  const int*   eidx  = (const int*)  d_in[1];
  const int*   batch = (const int*)  d_in[2];
  const int*   paths = (const int*)  d_in[3];
  const float* w1l   = (const float*)d_in[4];
  const float* b1l   = (const float*)d_in[5];
  const float* w1r   = (const float*)d_in[6];
  const float* w2l   = (const float*)d_in[7];
  const float* b2l   = (const float*)d_in[8];
  const float* w2r   = (const float*)d_in[9];
  const float* w_ih  = (const float*)d_in[10];
  const float* w_hh  = (const float*)d_in[11];
  const float* b_ih  = (const float*)d_in[12];
  const float* b_hh  = (const float*)d_in[13];
  const float* wm1   = (const float*)d_in[14];
  const float* bm1   = (const float*)d_in[15];
  const float* wm2   = (const float*)d_in[16];
  const float* bm2   = (const float*)d_in[17];

  const int* src = eidx;        // edge_index[0]
  const int* dst = eidx + NE;   // edge_index[1]

  // workspace layout (floats), offsets multiples of 16 floats
  float* w    = (float*)d_ws;
  float* bufA = w;                         // N*256 (mean agg; layer-2 output in-place)
  float* bufB = bufA + (long long)NN*ND;   // N*256 (h1)
  float* xg   = bufB + (long long)NN*ND;   // 2048*1024 floats
  float* gsum = xg   + 2048*1024;          // 64*256
  float* gcnt = gsum + NB*ND;              // 64
  float* h0   = gcnt + 64;                 // 64*256
  float* c0   = h0   + NB*ND;              // 64*256
  float* h1   = c0   + NB*ND;              // 64*256
  float* comb = h1   + NB*ND;              // 64*512
  ushort* wt1H = (ushort*)(comb + NB*512); // 256*512 each (bf16)
  ushort* wt1L = wt1H + 256*512;
  ushort* wt2H = wt1L + 256*512;
  ushort* wt2L = wt2H + 256*512;

  // CSR scratch aliased into xg region (dead until k_xgate runs, after layer 2)
  int* cnt    = (int*)xg;        // 50432
  int* offs   = cnt    + 50432;  // 50432
  int* cursor = offs   + 50432;  // 50432
  int* bsum   = cursor + 50432;  // 256
  int* bsum2  = bsum   + 256;    // 256
  int* csr    = bsum2  + 256;    // 800000

  // ---- weight prep (transpose + bf16 hi/lo split) ----
  k_wsplit<<<512, 256, 0, stream>>>(w1l, w1r, wt1H, wt1L);
  k_wsplit<<<512, 256, 0, stream>>>(w2l, w2r, wt2H, wt2L);

  // ---- build CSR (counting sort by dst), shared by both layers ----
  hipMemsetAsync(cnt, 0, 50432*sizeof(int), stream);
  k_hist<<<1024, 256, 0, stream>>>(dst, cnt);
  k_scan_block<<<NSCAN, 256, 0, stream>>>(cnt, offs, bsum);
  k_scan_top<<<1, 256, 0, stream>>>(bsum, bsum2);
  k_scan_add<<<NSCAN, 256, 0, stream>>>(offs, bsum2, cursor);
  k_fill<<<1024, 256, 0, stream>>>(src, dst, cursor, csr);

  // ---- layer 1: gather-mean then MFMA GEMM ----
  k_gather<<<NN, 256, 0, stream>>>(x, offs, csr, bufA);
  k_gemm_mfma<<<(NN+63)/64, 256, 0, stream>>>(bufA, x, wt1H, wt1L, b1l, bufB, 1);

  // ---- layer 2 (node_emb written in-place over bufA) ----
  k_gather<<<NN, 256, 0, stream>>>(bufB, offs, csr, bufA);
  k_gemm_mfma<<<(NN+63)/64, 256, 0, stream>>>(bufA, bufB, wt2H, wt2L, b2l, bufA, 0);

  // ---- global mean pool ----
  hipMemsetAsync(gsum, 0, (NB*ND + 64)*sizeof(float), stream);
  k_pool<<<(NN+255)/256, 256, 0, stream>>>(bufA, batch, gsum, gcnt);

  // ---- LSTM input gates (overwrites the CSR alias region — CSR dead by now) ----
  k_xgate<<<dim3((NB*NL)/64, 1024/256), 256, 0, stream>>>(bufA, paths, w_ih, b_ih, b_hh, xg);

  // ---- LSTM recurrence: 32 steps, ping-pong h buffers ----
  hipMemsetAsync(h0, 0, 2*(size_t)NB*ND*sizeof(float), stream);  // h0 + c0
  for (int ts = 0; ts < NL; ++ts){
    float* hin  = (ts & 1) ? h1 : h0;
    float* hout = (ts & 1) ? h0 : h1;
    k_lstm_step<<<512, 256, 0, stream>>>(hin, hout, c0, xg, w_hh, ts);
  }

  // ---- concat + scorer ----
  k_final<<<NB, 256, 0, stream>>>(gsum, gcnt, h0, comb);
  k_score<<<NB, 256, 0, stream>>>(comb, wm1, bm1, wm2, bm2, (float*)d_out);
}

// Round 6
// 942.883 us; speedup vs baseline: 6.6396x; 1.0942x over previous
//
#include <hip/hip_runtime.h>

namespace {

constexpr int NN = 50000;   // nodes
constexpr int NE = 800000;  // edges
constexpr int NB = 64;      // graphs / batch
constexpr int NL = 32;      // path length
constexpr int ND = 256;     // D == H == 256
constexpr int NSCAN = 196;  // ceil(50176/256) scan blocks

typedef __attribute__((ext_vector_type(8))) short short8v;  // 8 bf16 (4 VGPRs)
typedef __attribute__((ext_vector_type(4))) float float4v;  // MFMA accumulator

__device__ __forceinline__ float sigf(float x){ return 1.0f/(1.0f + __expf(-x)); }

// split 8 fp32 -> 8 bf16-hi (truncated; exact bits) + 8 bf16-lo (of remainder)
__device__ __forceinline__ void split8(float4 fa, float4 fb, uint4& h, uint4& lo){
  uint a0=__float_as_uint(fa.x), a1=__float_as_uint(fa.y), a2=__float_as_uint(fa.z), a3=__float_as_uint(fa.w);
  uint b0=__float_as_uint(fb.x), b1=__float_as_uint(fb.y), b2=__float_as_uint(fb.z), b3=__float_as_uint(fb.w);
  h.x = (a0>>16) | (a1 & 0xFFFF0000u);
  h.y = (a2>>16) | (a3 & 0xFFFF0000u);
  h.z = (b0>>16) | (b1 & 0xFFFF0000u);
  h.w = (b2>>16) | (b3 & 0xFFFF0000u);
  float r0 = fa.x - __uint_as_float(a0 & 0xFFFF0000u);
  float r1 = fa.y - __uint_as_float(a1 & 0xFFFF0000u);
  float r2 = fa.z - __uint_as_float(a2 & 0xFFFF0000u);
  float r3 = fa.w - __uint_as_float(a3 & 0xFFFF0000u);
  float r4 = fb.x - __uint_as_float(b0 & 0xFFFF0000u);
  float r5 = fb.y - __uint_as_float(b1 & 0xFFFF0000u);
  float r6 = fb.z - __uint_as_float(b2 & 0xFFFF0000u);
  float r7 = fb.w - __uint_as_float(b3 & 0xFFFF0000u);
  lo.x = (__float_as_uint(r0)>>16) | (__float_as_uint(r1) & 0xFFFF0000u);
  lo.y = (__float_as_uint(r2)>>16) | (__float_as_uint(r3) & 0xFFFF0000u);
  lo.z = (__float_as_uint(r4)>>16) | (__float_as_uint(r5) & 0xFFFF0000u);
  lo.w = (__float_as_uint(r6)>>16) | (__float_as_uint(r7) & 0xFFFF0000u);
}

// ================= CSR build (counting sort of edges by dst) =================
__global__ void k_hist(const int* __restrict__ dst, int* __restrict__ cnt){
  int stride = gridDim.x * blockDim.x;
  for (int e = blockIdx.x*blockDim.x + threadIdx.x; e < NE; e += stride)
    atomicAdd(&cnt[dst[e]], 1);
}

__global__ void k_scan_block(const int* __restrict__ cnt, int* __restrict__ offs,
                             int* __restrict__ bsum){
  __shared__ int s[256];
  const int t = threadIdx.x, i = blockIdx.x*256 + t;
  int v = cnt[i];
  s[t] = v; __syncthreads();
  #pragma unroll
  for (int off = 1; off < 256; off <<= 1){
    int x = (t >= off) ? s[t-off] : 0;
    __syncthreads();
    s[t] += x;
    __syncthreads();
  }
  offs[i] = s[t] - v;
  if (t == 255) bsum[blockIdx.x] = s[255];
}

__global__ void k_scan_top(const int* __restrict__ bsum, int* __restrict__ bsum2){
  __shared__ int s[256];
  const int t = threadIdx.x;
  int v = (t < NSCAN) ? bsum[t] : 0;
  s[t] = v; __syncthreads();
  #pragma unroll
  for (int off = 1; off < 256; off <<= 1){
    int x = (t >= off) ? s[t-off] : 0;
    __syncthreads();
    s[t] += x;
    __syncthreads();
  }
  if (t < NSCAN) bsum2[t] = s[t] - v;
}

__global__ void k_scan_add(int* __restrict__ offs, const int* __restrict__ bsum2,
                           int* __restrict__ cursor){
  const int i = blockIdx.x*256 + threadIdx.x;
  int v = offs[i] + bsum2[blockIdx.x];
  offs[i] = v;
  cursor[i] = v;
}

__global__ void k_fill(const int* __restrict__ src, const int* __restrict__ dst,
                       int* __restrict__ cursor, int* __restrict__ csr){
  int stride = gridDim.x * blockDim.x;
  for (int e = blockIdx.x*blockDim.x + threadIdx.x; e < NE; e += stride){
    int d = dst[e];
    int pos = atomicAdd(&cursor[d], 1);
    csr[pos] = src[e];
  }
}

// ================= mean-aggregate gather: one block per dst node =================
__launch_bounds__(256, 8)
__global__ void k_gather(const float* __restrict__ feat, const int* __restrict__ offs,
                         const int* __restrict__ csr, float* __restrict__ out){
  const int u = blockIdx.x, t = threadIdx.x;
  const int beg = offs[u], end = offs[u+1];
  __shared__ int sidx[256];
  float acc = 0.f;
  for (int c = beg; c < end; c += 256){
    int n = min(256, end - c);
    __syncthreads();
    if (t < n) sidx[t] = csr[c + t];
    __syncthreads();
    int j = 0;
    for (; j + 4 <= n; j += 4){
      int s0 = sidx[j], s1 = sidx[j+1], s2 = sidx[j+2], s3 = sidx[j+3];
      float v0 = feat[(long long)s0*ND + t];
      float v1 = feat[(long long)s1*ND + t];
      float v2 = feat[(long long)s2*ND + t];
      float v3 = feat[(long long)s3*ND + t];
      acc += (v0 + v1) + (v2 + v3);
    }
    for (; j < n; ++j) acc += feat[(long long)sidx[j]*ND + t];
  }
  float d = (float)(end - beg);
  out[(long long)u*ND + t] = acc / fmaxf(d, 1.f);
}

// ============ weight prep: fragment-linear swizzled [wl; wr] bf16 hi/lo ============
// Layout (16B chunks of 8 bf16): chunk[((wc*4+nt)*16 + kk)*64 + lq*16 + lm] holds
// Wt[col = wc*64+nt*16+lm][k = kk*32 + lq*8 .. +8]. GEMM B-fragment loads are then
// 64 contiguous lanes x 16B = fully-coalesced 1KB per instruction.
__global__ void k_wsplit(const float* __restrict__ wl, const float* __restrict__ wr,
                         ushort* __restrict__ WtH, ushort* __restrict__ WtL){
  const int k = blockIdx.x;    // 0..511
  const int n = threadIdx.x;   // 0..255
  float v = (k < 256) ? wl[k*256 + n] : wr[(k-256)*256 + n];
  uint u = __float_as_uint(v);
  float r = v - __uint_as_float(u & 0xFFFF0000u);
  const int wc = n >> 6, nt = (n >> 4) & 3, lm = n & 15;
  const int kk = k >> 5, lq = (k >> 3) & 3, j = k & 7;
  const long long idx = (long long)(((wc*4 + nt)*16 + kk)*64 + lq*16 + lm)*8 + j;
  WtH[idx] = (ushort)(u >> 16);
  WtL[idx] = (ushort)(__float_as_uint(r) >> 16);
}

// ============ MFMA SAGE GEMM: barrier-free main loop + distance-1 prefetch ============
// C = act([A1|A2] @ Wt^T + bias), bf16 3-term split. Block: 64 rows x 256 cols, 4 waves;
// wave w covers cols w*64..w*64+63 (4 n-tiles). K=512 (kk 0..7 -> A1, 8..15 -> A2), BK=32.
// B: fragment-linear swizzled global (coalesced 1KB loads). A: direct loads, rows CLAMPED
// (branchless -> hoistable); bogus tail rows discarded by epilogue guard. Fully-unrolled
// K-loop with double-buffered fragments keeps 16 loads in flight under each 48-MFMA burst.
// Epilogue stages 16x256 slabs through LDS for coalesced float4 stores. In-place C==A1 safe.
__launch_bounds__(256, 2)
__global__ void k_gemm_mfma(const float* __restrict__ A1, const float* __restrict__ A2,
                            const ushort* __restrict__ WtH, const ushort* __restrict__ WtL,
                            const float* __restrict__ bias, float* __restrict__ C, int relu)
{
  __shared__ float eb[16*260];     // epilogue staging (16.6 KB)
  const int t  = threadIdx.x;
  const int w  = t >> 6;           // wave 0..3
  const int l  = t & 63;           // lane
  const int lm = l & 15;
  const int lq = l >> 4;
  const int m0 = blockIdx.x * 64;

  const uint4* BH4 = (const uint4*)WtH;
  const uint4* BL4 = (const uint4*)WtL;

  const float4v vzero = {0.f, 0.f, 0.f, 0.f};
  float4v acc[4][4];
  #pragma unroll
  for (int i = 0; i < 4; ++i)
    #pragma unroll
    for (int j = 0; j < 4; ++j) acc[i][j] = vzero;

  long long arow[4];
  #pragma unroll
  for (int mt = 0; mt < 4; ++mt){
    int row = m0 + mt*16 + lm;
    row = (row < NN) ? row : (NN - 1);          // clamp: branchless, dup rows discarded later
    arow[mt] = (long long)row * ND;
  }
  int bbase[4];
  #pragma unroll
  for (int nt = 0; nt < 4; ++nt) bbase[nt] = (w*4 + nt)*1024 + l;

  auto ldB = [&](int kk, uint4* bh, uint4* bl){
    #pragma unroll
    for (int nt = 0; nt < 4; ++nt){
      int idx = bbase[nt] + kk*64;
      bh[nt] = BH4[idx];
      bl[nt] = BL4[idx];
    }
  };
  auto ldA = [&](int kk, uint4* ah, uint4* al){
    const float* Ab = (kk < 8) ? A1 : A2;       // constant-folds under full unroll
    const int koff = (kk & 7)*32 + lq*8;
    #pragma unroll
    for (int mt = 0; mt < 4; ++mt){
      const float* p = Ab + arow[mt] + koff;
      float4 fa = *(const float4*)p;
      float4 fb = *(const float4*)(p + 4);
      split8(fa, fb, ah[mt], al[mt]);
    }
  };

  uint4 bhb[2][4], blb[2][4], ahb[2][4], alb[2][4];
  ldB(0, bhb[0], blb[0]);
  ldA(0, ahb[0], alb[0]);

  #pragma unroll
  for (int kk = 0; kk < 16; ++kk){
    const int cur = kk & 1, nx = cur ^ 1;
    if (kk < 15){                               // constant under unroll
      ldB(kk + 1, bhb[nx], blb[nx]);
      ldA(kk + 1, ahb[nx], alb[nx]);
    }
    #pragma unroll
    for (int nt = 0; nt < 4; ++nt){
      short8v bh = *(short8v*)&bhb[cur][nt];
      short8v bl = *(short8v*)&blb[cur][nt];
      #pragma unroll
      for (int mt = 0; mt < 4; ++mt){
        short8v ah = *(short8v*)&ahb[cur][mt];
        short8v al = *(short8v*)&alb[cur][mt];
        acc[mt][nt] = __builtin_amdgcn_mfma_f32_16x16x32_bf16(ah, bh, acc[mt][nt], 0, 0, 0);
        acc[mt][nt] = __builtin_amdgcn_mfma_f32_16x16x32_bf16(al, bh, acc[mt][nt], 0, 0, 0);
        acc[mt][nt] = __builtin_amdgcn_mfma_f32_16x16x32_bf16(ah, bl, acc[mt][nt], 0, 0, 0);
      }
    }
  }

  // ---- epilogue: LDS transpose per 16-row slab, coalesced float4 stores ----
  float bvv[4];
  #pragma unroll
  for (int nt = 0; nt < 4; ++nt) bvv[nt] = bias[w*64 + nt*16 + lm];

  #pragma unroll
  for (int mt = 0; mt < 4; ++mt){
    #pragma unroll
    for (int nt = 0; nt < 4; ++nt){
      #pragma unroll
      for (int r = 0; r < 4; ++r){
        float v = acc[mt][nt][r] + bvv[nt];
        if (relu) v = fmaxf(v, 0.f);
        eb[(lq*4 + r)*260 + w*64 + nt*16 + lm] = v;   // C/D: col=lane&15, row=quad*4+reg
      }
    }
    __syncthreads();
    #pragma unroll
    for (int i = 0; i < 4; ++i){
      int idx = i*256 + t;           // 0..1023
      int rr  = idx >> 6;            // 0..15
      int c4  = (idx & 63) * 4;      // 0..252
      int grow = m0 + mt*16 + rr;
      if (grow < NN)
        *(float4*)(C + (long long)grow*ND + c4) = *(float4*)&eb[rr*260 + c4];
    }
    __syncthreads();
  }
}

// ---------------- LSTM input gates: Xg[i][g] = emb[paths[i]] . w_ih[g] + b_ih[g]+b_hh[g] ----------------
__launch_bounds__(256, 3)
__global__ void k_xgate(const float* __restrict__ emb, const int* __restrict__ paths,
                        const float* __restrict__ w_ih, const float* __restrict__ b_ih,
                        const float* __restrict__ b_hh, float* __restrict__ xg)
{
  __shared__ float As[16][68];
  __shared__ float Ws[16][260];
  const int t  = threadIdx.x;
  const int m0 = blockIdx.x * 64;    // path rows (2048 total)
  const int g0 = blockIdx.y * 256;   // gate cols (1024 total)
  const int rg = t >> 5, cg = t & 31;
  const int sm = t >> 2, sj = (t & 3) * 4;

  float acc[8][8];
  #pragma unroll
  for (int i = 0; i < 8; ++i)
    #pragma unroll
    for (int j = 0; j < 8; ++j) acc[i][j] = 0.f;

  const int node = paths[m0 + sm];
  const float* arow = emb  + (long long)node*ND;
  const float* wrow = w_ih + (long long)(g0 + t)*ND;

  for (int k0 = 0; k0 < 256; k0 += 16){
    float4 av = *(const float4*)(arow + k0 + sj);
    float4 q0 = *(const float4*)(wrow + k0 + 0);
    float4 q1 = *(const float4*)(wrow + k0 + 4);
    float4 q2 = *(const float4*)(wrow + k0 + 8);
    float4 q3 = *(const float4*)(wrow + k0 + 12);
    __syncthreads();
    As[sj+0][sm]=av.x; As[sj+1][sm]=av.y; As[sj+2][sm]=av.z; As[sj+3][sm]=av.w;
    Ws[ 0][t]=q0.x; Ws[ 1][t]=q0.y; Ws[ 2][t]=q0.z; Ws[ 3][t]=q0.w;
    Ws[ 4][t]=q1.x; Ws[ 5][t]=q1.y; Ws[ 6][t]=q1.z; Ws[ 7][t]=q1.w;
    Ws[ 8][t]=q2.x; Ws[ 9][t]=q2.y; Ws[10][t]=q2.z; Ws[11][t]=q2.w;
    Ws[12][t]=q3.x; Ws[13][t]=q3.y; Ws[14][t]=q3.z; Ws[15][t]=q3.w;
    __syncthreads();
    #pragma unroll
    for (int k = 0; k < 16; ++k){
      float a[8], b[8];
      *(float4*)&a[0] = *(const float4*)&As[k][rg*8];
      *(float4*)&a[4] = *(const float4*)&As[k][rg*8+4];
      *(float4*)&b[0] = *(const float4*)&Ws[k][cg*8];
      *(float4*)&b[4] = *(const float4*)&Ws[k][cg*8+4];
      #pragma unroll
      for (int i = 0; i < 8; ++i)
        #pragma unroll
        for (int j = 0; j < 8; ++j)
          acc[i][j] = fmaf(a[i], b[j], acc[i][j]);
    }
  }

  float bv[8];
  #pragma unroll
  for (int j = 0; j < 8; ++j){ int g = g0 + cg*8 + j; bv[j] = b_ih[g] + b_hh[g]; }
  #pragma unroll
  for (int i = 0; i < 8; ++i){
    int row = m0 + rg*8 + i;
    float o[8];
    #pragma unroll
    for (int j = 0; j < 8; ++j) o[j] = acc[i][j] + bv[j];
    *(float4*)(xg + (long long)row*1024 + g0 + cg*8 + 0) = *(float4*)&o[0];
    *(float4*)(xg + (long long)row*1024 + g0 + cg*8 + 4) = *(float4*)&o[4];
  }
}

// ---------------- one LSTM step ----------------
__launch_bounds__(256, 4)
__global__ void k_lstm_step(const float* __restrict__ h_in, float* __restrict__ h_out,
                            float* __restrict__ c_state, const float* __restrict__ xg,
                            const float* __restrict__ w_hh, int tstep)
{
  __shared__ float ws[4*256];
  __shared__ float hs[32*260];
  __shared__ float part[2*128];
  __shared__ float gs[128];
  const int t  = threadIdx.x;
  const int u  = blockIdx.x >> 1;
  const int b0 = (blockIdx.x & 1) * 32;

  {
    int gate = t >> 6, c4 = (t & 63) * 4;
    float4 v = *(const float4*)(w_hh + (long long)(gate*256 + u)*256 + c4);
    *(float4*)&ws[gate*256 + c4] = v;
  }
  #pragma unroll
  for (int i = 0; i < 8; ++i){
    int idx = i*256 + t;
    int b = idx >> 6, c4 = (idx & 63) * 4;
    float4 v = *(const float4*)(h_in + (long long)(b0 + b)*256 + c4);
    *(float4*)&hs[b*260 + c4] = v;
  }
  __syncthreads();

  const int b  = t & 31;
  const int g  = (t >> 5) & 3;
  const int kd = t >> 7;
  float s = 0.f;
  const float* hp = &hs[b*260 + kd*128];
  const float* wp = &ws[g*256 + kd*128];
  #pragma unroll
  for (int k4 = 0; k4 < 32; ++k4){
    float4 h4 = *(const float4*)(hp + k4*4);
    float4 w4 = *(const float4*)(wp + k4*4);
    s += h4.x*w4.x + h4.y*w4.y + h4.z*w4.z + h4.w*w4.w;
  }
  part[kd*128 + b*4 + g] = s;
  __syncthreads();

  if (t < 128){
    int bb = t >> 2, gg = t & 3;
    const float* xp = xg + ((long long)(b0 + bb)*NL + tstep)*1024;
    gs[t] = part[t] + part[128 + t] + xp[gg*256 + u];
  }
  __syncthreads();

  if (t < 32){
    float gi = gs[t*4+0], gf = gs[t*4+1], gG = gs[t*4+2], go = gs[t*4+3];
    int bb = b0 + t;
    float c_old = c_state[bb*256 + u];
    float c_new = sigf(gf)*c_old + sigf(gi)*tanhf(gG);
    c_state[bb*256 + u] = c_new;
    h_out[bb*256 + u] = sigf(go)*tanhf(c_new);
  }
}

// ---------------- global mean pool ----------------
__global__ void k_pool(const float* __restrict__ emb, const int* __restrict__ batch,
                       float* __restrict__ gsum, float* __restrict__ gcnt)
{
  __shared__ int bs[256];
  const int t  = threadIdx.x;
  const int n0 = blockIdx.x * 256;
  {
    int n = n0 + t;
    bs[t] = (n < NN) ? batch[n] : -1;
  }
  __syncthreads();
  int cur = bs[0];
  float acc = 0.f; int cnt = 0;
  for (int j = 0; j < 256; ++j){
    int nn = n0 + j;
    if (nn >= NN) break;
    int g = bs[j];
    if (g != cur){
      unsafeAtomicAdd(&gsum[cur*256 + t], acc);
      if (t == 0) unsafeAtomicAdd(&gcnt[cur], (float)cnt);
      acc = 0.f; cnt = 0; cur = g;
    }
    acc += emb[(long long)nn*256 + t];
    ++cnt;
  }
  if (cnt > 0 && cur >= 0){
    unsafeAtomicAdd(&gsum[cur*256 + t], acc);
    if (t == 0) unsafeAtomicAdd(&gcnt[cur], (float)cnt);
  }
}

// ---------------- finalize pooling + concat ----------------
__global__ void k_final(const float* __restrict__ gsum, const float* __restrict__ gcnt,
                        const float* __restrict__ hfin, float* __restrict__ comb)
{
  const int b = blockIdx.x, t = threadIdx.x;
  float r = 1.0f / fmaxf(gcnt[b], 1.0f);
  comb[b*512 + t]       = gsum[b*256 + t] * r;
  comb[b*512 + 256 + t] = hfin[b*256 + t];
}

// ---------------- scorer MLP ----------------
__global__ void k_score(const float* __restrict__ comb, const float* __restrict__ wm1,
                        const float* __restrict__ bm1, const float* __restrict__ wm2,
                        const float* __restrict__ bm2, float* __restrict__ out)
{
  __shared__ float cs[512];
  __shared__ float red[4];
  const int b = blockIdx.x, t = threadIdx.x;
  if (t < 128) *(float4*)&cs[t*4] = *(const float4*)&comb[b*512 + t*4];
  __syncthreads();
  float v = 0.f;
  #pragma unroll 4
  for (int k = 0; k < 512; ++k) v = fmaf(cs[k], wm1[(long long)k*256 + t], v);
  v = fmaxf(v + bm1[t], 0.f) * wm2[t];
  #pragma unroll
  for (int off = 32; off > 0; off >>= 1) v += __shfl_down(v, off, 64);
  if ((t & 63) == 0) red[t >> 6] = v;
  __syncthreads();
  if (t == 0) out[b] = red[0] + red[1] + red[2] + red[3] + bm2[0];
}

} // namespace

extern "C" void kernel_launch(void* const* d_in, const int* in_sizes, int n_in,
                              void* d_out, int out_size, void* d_ws, size_t ws_size,
                              hipStream_t stream)
{
  const float* x     = (const float*)d_in[0];
  const int*   eidx  = (const int*)  d_in[1];
  const int*   batch = (const int*)  d_in[2];
  const int*   paths = (const int*)  d_in[3];
  const float* w1l   = (const float*)d_in[4];
  const float* b1l   = (const float*)d_in[5];
  const float* w1r   = (const float*)d_in[6];
  const float* w2l   = (const float*)d_in[7];
  const float* b2l   = (const float*)d_in[8];
  const float* w2r   = (const float*)d_in[9];
  const float* w_ih  = (const float*)d_in[10];
  const float* w_hh  = (const float*)d_in[11];
  const float* b_ih  = (const float*)d_in[12];
  const float* b_hh  = (const float*)d_in[13];
  const float* wm1   = (const float*)d_in[14];
  const float* bm1   = (const float*)d_in[15];
  const float* wm2   = (const float*)d_in[16];
  const float* bm2   = (const float*)d_in[17];

  const int* src = eidx;        // edge_index[0]
  const int* dst = eidx + NE;   // edge_index[1]

  // workspace layout (floats), offsets multiples of 16 floats
  float* w    = (float*)d_ws;
  float* bufA = w;                         // N*256 (mean agg; layer-2 output in-place)
  float* bufB = bufA + (long long)NN*ND;   // N*256 (h1)
  float* xg   = bufB + (long long)NN*ND;   // 2048*1024 floats
  float* gsum = xg   + 2048*1024;          // 64*256
  float* gcnt = gsum + NB*ND;              // 64
  float* h0   = gcnt + 64;                 // 64*256
  float* c0   = h0   + NB*ND;              // 64*256
  float* h1   = c0   + NB*ND;              // 64*256
  float* comb = h1   + NB*ND;              // 64*512
  ushort* wt1H = (ushort*)(comb + NB*512); // 256*512 each (bf16, fragment-swizzled)
  ushort* wt1L = wt1H + 256*512;
  ushort* wt2H = wt1L + 256*512;
  ushort* wt2L = wt2H + 256*512;

  // CSR scratch aliased into xg region (dead until k_xgate runs, after layer 2)
  int* cnt    = (int*)xg;        // 50432
  int* offs   = cnt    + 50432;  // 50432
  int* cursor = offs   + 50432;  // 50432
  int* bsum   = cursor + 50432;  // 256
  int* bsum2  = bsum   + 256;    // 256
  int* csr    = bsum2  + 256;    // 800000

  // ---- weight prep (fragment-swizzled bf16 hi/lo split) ----
  k_wsplit<<<512, 256, 0, stream>>>(w1l, w1r, wt1H, wt1L);
  k_wsplit<<<512, 256, 0, stream>>>(w2l, w2r, wt2H, wt2L);

  // ---- build CSR (counting sort by dst), shared by both layers ----
  hipMemsetAsync(cnt, 0, 50432*sizeof(int), stream);
  k_hist<<<1024, 256, 0, stream>>>(dst, cnt);
  k_scan_block<<<NSCAN, 256, 0, stream>>>(cnt, offs, bsum);
  k_scan_top<<<1, 256, 0, stream>>>(bsum, bsum2);
  k_scan_add<<<NSCAN, 256, 0, stream>>>(offs, bsum2, cursor);
  k_fill<<<1024, 256, 0, stream>>>(src, dst, cursor, csr);

  // ---- layer 1: gather-mean then MFMA GEMM ----
  k_gather<<<NN, 256, 0, stream>>>(x, offs, csr, bufA);
  k_gemm_mfma<<<(NN+63)/64, 256, 0, stream>>>(bufA, x, wt1H, wt1L, b1l, bufB, 1);

  // ---- layer 2 (node_emb written in-place over bufA) ----
  k_gather<<<NN, 256, 0, stream>>>(bufB, offs, csr, bufA);
  k_gemm_mfma<<<(NN+63)/64, 256, 0, stream>>>(bufA, bufB, wt2H, wt2L, b2l, bufA, 0);

  // ---- global mean pool ----
  hipMemsetAsync(gsum, 0, (NB*ND + 64)*sizeof(float), stream);
  k_pool<<<(NN+255)/256, 256, 0, stream>>>(bufA, batch, gsum, gcnt);

  // ---- LSTM input gates (overwrites the CSR alias region — CSR dead by now) ----
  k_xgate<<<dim3((NB*NL)/64, 1024/256), 256, 0, stream>>>(bufA, paths, w_ih, b_ih, b_hh, xg);

  // ---- LSTM recurrence: 32 steps, ping-pong h buffers ----
  hipMemsetAsync(h0, 0, 2*(size_t)NB*ND*sizeof(float), stream);  // h0 + c0
  for (int ts = 0; ts < NL; ++ts){
    float* hin  = (ts & 1) ? h1 : h0;
    float* hout = (ts & 1) ? h0 : h1;
    k_lstm_step<<<512, 256, 0, stream>>>(hin, hout, c0, xg, w_hh, ts);
  }

  // ---- concat + scorer ----
  k_final<<<NB, 256, 0, stream>>>(gsum, gcnt, h0, comb);
  k_score<<<NB, 256, 0, stream>>>(comb, wm1, bm1, wm2, bm2, (float*)d_out);
}

// Round 7
// 941.649 us; speedup vs baseline: 6.6482x; 1.0013x over previous
//
#include <hip/hip_runtime.h>

namespace {

constexpr int NN = 50000;   // nodes
constexpr int NE = 800000;  // edges
constexpr int NB = 64;      // graphs / batch
constexpr int NL = 32;      // path length
constexpr int ND = 256;     // D == H == 256
constexpr int NSCAN = 196;  // ceil(50176/256) scan blocks

typedef __attribute__((ext_vector_type(8))) short short8v;  // 8 bf16 (4 VGPRs)
typedef __attribute__((ext_vector_type(4))) float float4v;  // MFMA accumulator

__device__ __forceinline__ float sigf(float x){ return 1.0f/(1.0f + __expf(-x)); }

// split 8 fp32 -> 8 bf16-hi (truncated; exact bits) + 8 bf16-lo (of remainder)
__device__ __forceinline__ void split8(float4 fa, float4 fb, uint4& h, uint4& lo){
  uint a0=__float_as_uint(fa.x), a1=__float_as_uint(fa.y), a2=__float_as_uint(fa.z), a3=__float_as_uint(fa.w);
  uint b0=__float_as_uint(fb.x), b1=__float_as_uint(fb.y), b2=__float_as_uint(fb.z), b3=__float_as_uint(fb.w);
  h.x = (a0>>16) | (a1 & 0xFFFF0000u);
  h.y = (a2>>16) | (a3 & 0xFFFF0000u);
  h.z = (b0>>16) | (b1 & 0xFFFF0000u);
  h.w = (b2>>16) | (b3 & 0xFFFF0000u);
  float r0 = fa.x - __uint_as_float(a0 & 0xFFFF0000u);
  float r1 = fa.y - __uint_as_float(a1 & 0xFFFF0000u);
  float r2 = fa.z - __uint_as_float(a2 & 0xFFFF0000u);
  float r3 = fa.w - __uint_as_float(a3 & 0xFFFF0000u);
  float r4 = fb.x - __uint_as_float(b0 & 0xFFFF0000u);
  float r5 = fb.y - __uint_as_float(b1 & 0xFFFF0000u);
  float r6 = fb.z - __uint_as_float(b2 & 0xFFFF0000u);
  float r7 = fb.w - __uint_as_float(b3 & 0xFFFF0000u);
  lo.x = (__float_as_uint(r0)>>16) | (__float_as_uint(r1) & 0xFFFF0000u);
  lo.y = (__float_as_uint(r2)>>16) | (__float_as_uint(r3) & 0xFFFF0000u);
  lo.z = (__float_as_uint(r4)>>16) | (__float_as_uint(r5) & 0xFFFF0000u);
  lo.w = (__float_as_uint(r6)>>16) | (__float_as_uint(r7) & 0xFFFF0000u);
}

// ================= CSR build (counting sort of edges by dst) =================
__global__ void k_hist(const int* __restrict__ dst, int* __restrict__ cnt){
  int stride = gridDim.x * blockDim.x;
  for (int e = blockIdx.x*blockDim.x + threadIdx.x; e < NE; e += stride)
    atomicAdd(&cnt[dst[e]], 1);
}

__global__ void k_scan_block(const int* __restrict__ cnt, int* __restrict__ offs,
                             int* __restrict__ bsum){
  __shared__ int s[256];
  const int t = threadIdx.x, i = blockIdx.x*256 + t;
  int v = cnt[i];
  s[t] = v; __syncthreads();
  #pragma unroll
  for (int off = 1; off < 256; off <<= 1){
    int x = (t >= off) ? s[t-off] : 0;
    __syncthreads();
    s[t] += x;
    __syncthreads();
  }
  offs[i] = s[t] - v;
  if (t == 255) bsum[blockIdx.x] = s[255];
}

__global__ void k_scan_top(const int* __restrict__ bsum, int* __restrict__ bsum2){
  __shared__ int s[256];
  const int t = threadIdx.x;
  int v = (t < NSCAN) ? bsum[t] : 0;
  s[t] = v; __syncthreads();
  #pragma unroll
  for (int off = 1; off < 256; off <<= 1){
    int x = (t >= off) ? s[t-off] : 0;
    __syncthreads();
    s[t] += x;
    __syncthreads();
  }
  if (t < NSCAN) bsum2[t] = s[t] - v;
}

__global__ void k_scan_add(int* __restrict__ offs, const int* __restrict__ bsum2,
                           int* __restrict__ cursor){
  const int i = blockIdx.x*256 + threadIdx.x;
  int v = offs[i] + bsum2[blockIdx.x];
  offs[i] = v;
  cursor[i] = v;
}

__global__ void k_fill(const int* __restrict__ src, const int* __restrict__ dst,
                       int* __restrict__ cursor, int* __restrict__ csr){
  int stride = gridDim.x * blockDim.x;
  for (int e = blockIdx.x*blockDim.x + threadIdx.x; e < NE; e += stride){
    int d = dst[e];
    int pos = atomicAdd(&cursor[d], 1);
    csr[pos] = src[e];
  }
}

// ================= mean-aggregate gather: one block per dst node =================
// Wave per edge-row: lane l loads float4 at feat[src*256 + l*4] -> one 1KB row per
// vector instruction (16B/lane). 4 waves x unroll-2 = 8 rows in flight per block.
// Cross-wave reduction via 4KB LDS, one coalesced 1KB float4 store.
__launch_bounds__(256, 8)
__global__ void k_gather(const float* __restrict__ feat, const int* __restrict__ offs,
                         const int* __restrict__ csr, float* __restrict__ out){
  __shared__ float4 sp[256];
  const int u = blockIdx.x, t = threadIdx.x;
  const int w = t >> 6, l = t & 63;
  const int beg = offs[u], end = offs[u+1];
  const int lc = l * 4;
  float a0 = 0.f, a1 = 0.f, a2 = 0.f, a3 = 0.f;
  int e = beg + w;
  for (; e + 4 < end; e += 8){
    int s0 = csr[e], s1 = csr[e+4];
    const float4 v0 = *(const float4*)(feat + (long long)s0*ND + lc);
    const float4 v1 = *(const float4*)(feat + (long long)s1*ND + lc);
    a0 += v0.x + v1.x; a1 += v0.y + v1.y; a2 += v0.z + v1.z; a3 += v0.w + v1.w;
  }
  if (e < end){
    int s0 = csr[e];
    const float4 v0 = *(const float4*)(feat + (long long)s0*ND + lc);
    a0 += v0.x; a1 += v0.y; a2 += v0.z; a3 += v0.w;
  }
  sp[t] = make_float4(a0, a1, a2, a3);
  __syncthreads();
  if (t < 64){
    float4 p0 = sp[t], p1 = sp[64+t], p2 = sp[128+t], p3 = sp[192+t];
    float inv = 1.0f / fmaxf((float)(end - beg), 1.0f);
    float4 r;
    r.x = (p0.x + p1.x + p2.x + p3.x) * inv;
    r.y = (p0.y + p1.y + p2.y + p3.y) * inv;
    r.z = (p0.z + p1.z + p2.z + p3.z) * inv;
    r.w = (p0.w + p1.w + p2.w + p3.w) * inv;
    *(float4*)(out + (long long)u*ND + t*4) = r;
  }
}

// ============ weight prep: fragment-linear swizzled [wl; wr] bf16 hi/lo ============
__global__ void k_wsplit(const float* __restrict__ wl, const float* __restrict__ wr,
                         ushort* __restrict__ WtH, ushort* __restrict__ WtL){
  const int k = blockIdx.x;    // 0..511
  const int n = threadIdx.x;   // 0..255
  float v = (k < 256) ? wl[k*256 + n] : wr[(k-256)*256 + n];
  uint u = __float_as_uint(v);
  float r = v - __uint_as_float(u & 0xFFFF0000u);
  const int wc = n >> 6, nt = (n >> 4) & 3, lm = n & 15;
  const int kk = k >> 5, lq = (k >> 3) & 3, j = k & 7;
  const long long idx = (long long)(((wc*4 + nt)*16 + kk)*64 + lq*16 + lm)*8 + j;
  WtH[idx] = (ushort)(u >> 16);
  WtL[idx] = (ushort)(__float_as_uint(r) >> 16);
}

// ============ MFMA SAGE GEMM: barrier-free main loop + distance-1 prefetch ============
__launch_bounds__(256, 2)
__global__ void k_gemm_mfma(const float* __restrict__ A1, const float* __restrict__ A2,
                            const ushort* __restrict__ WtH, const ushort* __restrict__ WtL,
                            const float* __restrict__ bias, float* __restrict__ C, int relu)
{
  __shared__ float eb[16*260];     // epilogue staging (16.6 KB)
  const int t  = threadIdx.x;
  const int w  = t >> 6;           // wave 0..3
  const int l  = t & 63;           // lane
  const int lm = l & 15;
  const int lq = l >> 4;
  const int m0 = blockIdx.x * 64;

  const uint4* BH4 = (const uint4*)WtH;
  const uint4* BL4 = (const uint4*)WtL;

  const float4v vzero = {0.f, 0.f, 0.f, 0.f};
  float4v acc[4][4];
  #pragma unroll
  for (int i = 0; i < 4; ++i)
    #pragma unroll
    for (int j = 0; j < 4; ++j) acc[i][j] = vzero;

  long long arow[4];
  #pragma unroll
  for (int mt = 0; mt < 4; ++mt){
    int row = m0 + mt*16 + lm;
    row = (row < NN) ? row : (NN - 1);          // clamp: branchless, dup rows discarded later
    arow[mt] = (long long)row * ND;
  }
  int bbase[4];
  #pragma unroll
  for (int nt = 0; nt < 4; ++nt) bbase[nt] = (w*4 + nt)*1024 + l;

  auto ldB = [&](int kk, uint4* bh, uint4* bl){
    #pragma unroll
    for (int nt = 0; nt < 4; ++nt){
      int idx = bbase[nt] + kk*64;
      bh[nt] = BH4[idx];
      bl[nt] = BL4[idx];
    }
  };
  auto ldA = [&](int kk, uint4* ah, uint4* al){
    const float* Ab = (kk < 8) ? A1 : A2;       // constant-folds under full unroll
    const int koff = (kk & 7)*32 + lq*8;
    #pragma unroll
    for (int mt = 0; mt < 4; ++mt){
      const float* p = Ab + arow[mt] + koff;
      float4 fa = *(const float4*)p;
      float4 fb = *(const float4*)(p + 4);
      split8(fa, fb, ah[mt], al[mt]);
    }
  };

  uint4 bhb[2][4], blb[2][4], ahb[2][4], alb[2][4];
  ldB(0, bhb[0], blb[0]);
  ldA(0, ahb[0], alb[0]);

  #pragma unroll
  for (int kk = 0; kk < 16; ++kk){
    const int cur = kk & 1, nx = cur ^ 1;
    if (kk < 15){                               // constant under unroll
      ldB(kk + 1, bhb[nx], blb[nx]);
      ldA(kk + 1, ahb[nx], alb[nx]);
    }
    #pragma unroll
    for (int nt = 0; nt < 4; ++nt){
      short8v bh = *(short8v*)&bhb[cur][nt];
      short8v bl = *(short8v*)&blb[cur][nt];
      #pragma unroll
      for (int mt = 0; mt < 4; ++mt){
        short8v ah = *(short8v*)&ahb[cur][mt];
        short8v al = *(short8v*)&alb[cur][mt];
        acc[mt][nt] = __builtin_amdgcn_mfma_f32_16x16x32_bf16(ah, bh, acc[mt][nt], 0, 0, 0);
        acc[mt][nt] = __builtin_amdgcn_mfma_f32_16x16x32_bf16(al, bh, acc[mt][nt], 0, 0, 0);
        acc[mt][nt] = __builtin_amdgcn_mfma_f32_16x16x32_bf16(ah, bl, acc[mt][nt], 0, 0, 0);
      }
    }
  }

  // ---- epilogue: LDS transpose per 16-row slab, coalesced float4 stores ----
  float bvv[4];
  #pragma unroll
  for (int nt = 0; nt < 4; ++nt) bvv[nt] = bias[w*64 + nt*16 + lm];

  #pragma unroll
  for (int mt = 0; mt < 4; ++mt){
    #pragma unroll
    for (int nt = 0; nt < 4; ++nt){
      #pragma unroll
      for (int r = 0; r < 4; ++r){
        float v = acc[mt][nt][r] + bvv[nt];
        if (relu) v = fmaxf(v, 0.f);
        eb[(lq*4 + r)*260 + w*64 + nt*16 + lm] = v;   // C/D: col=lane&15, row=quad*4+reg
      }
    }
    __syncthreads();
    #pragma unroll
    for (int i = 0; i < 4; ++i){
      int idx = i*256 + t;           // 0..1023
      int rr  = idx >> 6;            // 0..15
      int c4  = (idx & 63) * 4;      // 0..252
      int grow = m0 + mt*16 + rr;
      if (grow < NN)
        *(float4*)(C + (long long)grow*ND + c4) = *(float4*)&eb[rr*260 + c4];
    }
    __syncthreads();
  }
}

// ---------------- LSTM input gates: Xg[i][g] = emb[paths[i]] . w_ih[g] + b_ih[g]+b_hh[g] ----------------
__launch_bounds__(256, 3)
__global__ void k_xgate(const float* __restrict__ emb, const int* __restrict__ paths,
                        const float* __restrict__ w_ih, const float* __restrict__ b_ih,
                        const float* __restrict__ b_hh, float* __restrict__ xg)
{
  __shared__ float As[16][68];
  __shared__ float Ws[16][260];
  const int t  = threadIdx.x;
  const int m0 = blockIdx.x * 64;    // path rows (2048 total)
  const int g0 = blockIdx.y * 256;   // gate cols (1024 total)
  const int rg = t >> 5, cg = t & 31;
  const int sm = t >> 2, sj = (t & 3) * 4;

  float acc[8][8];
  #pragma unroll
  for (int i = 0; i < 8; ++i)
    #pragma unroll
    for (int j = 0; j < 8; ++j) acc[i][j] = 0.f;

  const int node = paths[m0 + sm];
  const float* arow = emb  + (long long)node*ND;
  const float* wrow = w_ih + (long long)(g0 + t)*ND;

  for (int k0 = 0; k0 < 256; k0 += 16){
    float4 av = *(const float4*)(arow + k0 + sj);
    float4 q0 = *(const float4*)(wrow + k0 + 0);
    float4 q1 = *(const float4*)(wrow + k0 + 4);
    float4 q2 = *(const float4*)(wrow + k0 + 8);
    float4 q3 = *(const float4*)(wrow + k0 + 12);
    __syncthreads();
    As[sj+0][sm]=av.x; As[sj+1][sm]=av.y; As[sj+2][sm]=av.z; As[sj+3][sm]=av.w;
    Ws[ 0][t]=q0.x; Ws[ 1][t]=q0.y; Ws[ 2][t]=q0.z; Ws[ 3][t]=q0.w;
    Ws[ 4][t]=q1.x; Ws[ 5][t]=q1.y; Ws[ 6][t]=q1.z; Ws[ 7][t]=q1.w;
    Ws[ 8][t]=q2.x; Ws[ 9][t]=q2.y; Ws[10][t]=q2.z; Ws[11][t]=q2.w;
    Ws[12][t]=q3.x; Ws[13][t]=q3.y; Ws[14][t]=q3.z; Ws[15][t]=q3.w;
    __syncthreads();
    #pragma unroll
    for (int k = 0; k < 16; ++k){
      float a[8], b[8];
      *(float4*)&a[0] = *(const float4*)&As[k][rg*8];
      *(float4*)&a[4] = *(const float4*)&As[k][rg*8+4];
      *(float4*)&b[0] = *(const float4*)&Ws[k][cg*8];
      *(float4*)&b[4] = *(const float4*)&Ws[k][cg*8+4];
      #pragma unroll
      for (int i = 0; i < 8; ++i)
        #pragma unroll
        for (int j = 0; j < 8; ++j)
          acc[i][j] = fmaf(a[i], b[j], acc[i][j]);
    }
  }

  float bv[8];
  #pragma unroll
  for (int j = 0; j < 8; ++j){ int g = g0 + cg*8 + j; bv[j] = b_ih[g] + b_hh[g]; }
  #pragma unroll
  for (int i = 0; i < 8; ++i){
    int row = m0 + rg*8 + i;
    float o[8];
    #pragma unroll
    for (int j = 0; j < 8; ++j) o[j] = acc[i][j] + bv[j];
    *(float4*)(xg + (long long)row*1024 + g0 + cg*8 + 0) = *(float4*)&o[0];
    *(float4*)(xg + (long long)row*1024 + g0 + cg*8 + 4) = *(float4*)&o[4];
  }
}

// ---------------- one LSTM step ----------------
__launch_bounds__(256, 4)
__global__ void k_lstm_step(const float* __restrict__ h_in, float* __restrict__ h_out,
                            float* __restrict__ c_state, const float* __restrict__ xg,
                            const float* __restrict__ w_hh, int tstep)
{
  __shared__ float ws[4*256];
  __shared__ float hs[32*260];
  __shared__ float part[2*128];
  __shared__ float gs[128];
  const int t  = threadIdx.x;
  const int u  = blockIdx.x >> 1;
  const int b0 = (blockIdx.x & 1) * 32;

  {
    int gate = t >> 6, c4 = (t & 63) * 4;
    float4 v = *(const float4*)(w_hh + (long long)(gate*256 + u)*256 + c4);
    *(float4*)&ws[gate*256 + c4] = v;
  }
  #pragma unroll
  for (int i = 0; i < 8; ++i){
    int idx = i*256 + t;
    int b = idx >> 6, c4 = (idx & 63) * 4;
    float4 v = *(const float4*)(h_in + (long long)(b0 + b)*256 + c4);
    *(float4*)&hs[b*260 + c4] = v;
  }
  __syncthreads();

  const int b  = t & 31;
  const int g  = (t >> 5) & 3;
  const int kd = t >> 7;
  float s = 0.f;
  const float* hp = &hs[b*260 + kd*128];
  const float* wp = &ws[g*256 + kd*128];
  #pragma unroll
  for (int k4 = 0; k4 < 32; ++k4){
    float4 h4 = *(const float4*)(hp + k4*4);
    float4 w4 = *(const float4*)(wp + k4*4);
    s += h4.x*w4.x + h4.y*w4.y + h4.z*w4.z + h4.w*w4.w;
  }
  part[kd*128 + b*4 + g] = s;
  __syncthreads();

  if (t < 128){
    int bb = t >> 2, gg = t & 3;
    const float* xp = xg + ((long long)(b0 + bb)*NL + tstep)*1024;
    gs[t] = part[t] + part[128 + t] + xp[gg*256 + u];
  }
  __syncthreads();

  if (t < 32){
    float gi = gs[t*4+0], gf = gs[t*4+1], gG = gs[t*4+2], go = gs[t*4+3];
    int bb = b0 + t;
    float c_old = c_state[bb*256 + u];
    float c_new = sigf(gf)*c_old + sigf(gi)*tanhf(gG);
    c_state[bb*256 + u] = c_new;
    h_out[bb*256 + u] = sigf(go)*tanhf(c_new);
  }
}

// ---------------- global mean pool ----------------
__global__ void k_pool(const float* __restrict__ emb, const int* __restrict__ batch,
                       float* __restrict__ gsum, float* __restrict__ gcnt)
{
  __shared__ int bs[256];
  const int t  = threadIdx.x;
  const int n0 = blockIdx.x * 256;
  {
    int n = n0 + t;
    bs[t] = (n < NN) ? batch[n] : -1;
  }
  __syncthreads();
  int cur = bs[0];
  float acc = 0.f; int cnt = 0;
  for (int j = 0; j < 256; ++j){
    int nn = n0 + j;
    if (nn >= NN) break;
    int g = bs[j];
    if (g != cur){
      unsafeAtomicAdd(&gsum[cur*256 + t], acc);
      if (t == 0) unsafeAtomicAdd(&gcnt[cur], (float)cnt);
      acc = 0.f; cnt = 0; cur = g;
    }
    acc += emb[(long long)nn*256 + t];
    ++cnt;
  }
  if (cnt > 0 && cur >= 0){
    unsafeAtomicAdd(&gsum[cur*256 + t], acc);
    if (t == 0) unsafeAtomicAdd(&gcnt[cur], (float)cnt);
  }
}

// ---------------- scorer MLP (pool-finalize + concat fused in) ----------------
__global__ void k_score(const float* __restrict__ gsum, const float* __restrict__ gcnt,
                        const float* __restrict__ hfin, const float* __restrict__ wm1,
                        const float* __restrict__ bm1, const float* __restrict__ wm2,
                        const float* __restrict__ bm2, float* __restrict__ out)
{
  __shared__ float cs[512];
  __shared__ float red[4];
  const int b = blockIdx.x, t = threadIdx.x;
  float inv = 1.0f / fmaxf(gcnt[b], 1.0f);
  cs[t]       = gsum[b*256 + t] * inv;
  cs[256 + t] = hfin[b*256 + t];
  __syncthreads();
  float v = 0.f;
  #pragma unroll 4
  for (int k = 0; k < 512; ++k) v = fmaf(cs[k], wm1[(long long)k*256 + t], v);
  v = fmaxf(v + bm1[t], 0.f) * wm2[t];
  #pragma unroll
  for (int off = 32; off > 0; off >>= 1) v += __shfl_down(v, off, 64);
  if ((t & 63) == 0) red[t >> 6] = v;
  __syncthreads();
  if (t == 0) out[b] = red[0] + red[1] + red[2] + red[3] + bm2[0];
}

} // namespace

extern "C" void kernel_launch(void* const* d_in, const int* in_sizes, int n_in,
                              void* d_out, int out_size, void* d_ws, size_t ws_size,
                              hipStream_t stream)
{
  const float* x     = (const float*)d_in[0];
  const int*   eidx  = (const int*)  d_in[1];
  const int*   batch = (const int*)  d_in[2];
  const int*   paths = (const int*)  d_in[3];
  const float* w1l   = (const float*)d_in[4];
  const float* b1l   = (const float*)d_in[5];
  const float* w1r   = (const float*)d_in[6];
  const float* w2l   = (const float*)d_in[7];
  const float* b2l   = (const float*)d_in[8];
  const float* w2r   = (const float*)d_in[9];
  const float* w_ih  = (const float*)d_in[10];
  const float* w_hh  = (const float*)d_in[11];
  const float* b_ih  = (const float*)d_in[12];
  const float* b_hh  = (const float*)d_in[13];
  const float* wm1   = (const float*)d_in[14];
  const float* bm1   = (const float*)d_in[15];
  const float* wm2   = (const float*)d_in[16];
  const float* bm2   = (const float*)d_in[17];

  const int* src = eidx;        // edge_index[0]
  const int* dst = eidx + NE;   // edge_index[1]

  // workspace layout (floats), offsets multiples of 16 floats
  float* w    = (float*)d_ws;
  float* bufA = w;                         // N*256 (mean agg; layer-2 output in-place)
  float* bufB = bufA + (long long)NN*ND;   // N*256 (h1)
  float* xg   = bufB + (long long)NN*ND;   // 2048*1024 floats
  float* gsum = xg   + 2048*1024;          // 64*256
  float* gcnt = gsum + NB*ND;              // 64
  float* h0   = gcnt + 64;                 // 64*256
  float* c0   = h0   + NB*ND;              // 64*256
  float* h1   = c0   + NB*ND;              // 64*256
  ushort* wt1H = (ushort*)(h1 + NB*ND);    // 256*512 each (bf16, fragment-swizzled)
  ushort* wt1L = wt1H + 256*512;
  ushort* wt2H = wt1L + 256*512;
  ushort* wt2L = wt2H + 256*512;

  // CSR scratch aliased into xg region (dead until k_xgate runs, after layer 2)
  int* cnt    = (int*)xg;        // 50432
  int* offs   = cnt    + 50432;  // 50432
  int* cursor = offs   + 50432;  // 50432
  int* bsum   = cursor + 50432;  // 256
  int* bsum2  = bsum   + 256;    // 256
  int* csr    = bsum2  + 256;    // 800000

  // ---- weight prep (fragment-swizzled bf16 hi/lo split) ----
  k_wsplit<<<512, 256, 0, stream>>>(w1l, w1r, wt1H, wt1L);
  k_wsplit<<<512, 256, 0, stream>>>(w2l, w2r, wt2H, wt2L);

  // ---- build CSR (counting sort by dst), shared by both layers ----
  hipMemsetAsync(cnt, 0, 50432*sizeof(int), stream);
  k_hist<<<1024, 256, 0, stream>>>(dst, cnt);
  k_scan_block<<<NSCAN, 256, 0, stream>>>(cnt, offs, bsum);
  k_scan_top<<<1, 256, 0, stream>>>(bsum, bsum2);
  k_scan_add<<<NSCAN, 256, 0, stream>>>(offs, bsum2, cursor);
  k_fill<<<1024, 256, 0, stream>>>(src, dst, cursor, csr);

  // ---- layer 1: gather-mean then MFMA GEMM ----
  k_gather<<<NN, 256, 0, stream>>>(x, offs, csr, bufA);
  k_gemm_mfma<<<(NN+63)/64, 256, 0, stream>>>(bufA, x, wt1H, wt1L, b1l, bufB, 1);

  // ---- layer 2 (node_emb written in-place over bufA) ----
  k_gather<<<NN, 256, 0, stream>>>(bufB, offs, csr, bufA);
  k_gemm_mfma<<<(NN+63)/64, 256, 0, stream>>>(bufA, bufB, wt2H, wt2L, b2l, bufA, 0);

  // ---- global mean pool ----
  hipMemsetAsync(gsum, 0, (NB*ND + 64)*sizeof(float), stream);
  k_pool<<<(NN+255)/256, 256, 0, stream>>>(bufA, batch, gsum, gcnt);

  // ---- LSTM input gates (overwrites the CSR alias region — CSR dead by now) ----
  k_xgate<<<dim3((NB*NL)/64, 1024/256), 256, 0, stream>>>(bufA, paths, w_ih, b_ih, b_hh, xg);

  // ---- LSTM recurrence: 32 steps, ping-pong h buffers ----
  hipMemsetAsync(h0, 0, 2*(size_t)NB*ND*sizeof(float), stream);  // h0 + c0
  for (int ts = 0; ts < NL; ++ts){
    float* hin  = (ts & 1) ? h1 : h0;
    float* hout = (ts & 1) ? h0 : h1;
    k_lstm_step<<<512, 256, 0, stream>>>(hin, hout, c0, xg, w_hh, ts);
  }

  // ---- fused concat + scorer ----
  k_score<<<NB, 256, 0, stream>>>(gsum, gcnt, h0, wm1, bm1, wm2, bm2, (float*)d_out);
}